// Round 1
// baseline (15455.644 us; speedup 1.0000x reference)
//
#include <hip/hip_runtime.h>
#include <hip/hip_bf16.h>

// ---------------------------------------------------------------------------
// DecoupledCls: 2-layer transformer encoder w/ prototype tokens + conv head.
// Round 1: correctness-first fp32 implementation.
//   - conv_query/key (1x1) folded into MHA in-proj:  W_eff = W_in @ w_conv
//   - flash-style attention (online softmax), 32x32 tiles, dh=128
//   - fused residual+LayerNorm
//   - Conv1d(k=3,pad=1) as 3-tap tiled GEMM
// Workspace: 5*(B*S*F) + B*S*DFF + 2*F*F + 2*F floats ~= 188 MB.
// ---------------------------------------------------------------------------

constexpr int BN = 4;        // batch
constexpr int TN = 2048;     // time
constexpr int FD = 1024;     // feature
constexpr int CP = 200;      // prototypes
constexpr int SN = TN + CP;  // 2248 tokens
constexpr int HN = 8;        // heads
constexpr int DH = 128;      // head dim
constexpr int DF = 128;      // ffn dim
constexpr int MR = BN * SN;  // 8992 rows flattened
constexpr float SCALE = 0.08838834764831845f;  // 1/sqrt(128)

// ---------------- build src: concat(x, prototypes-as-(F,C)) ----------------
__global__ __launch_bounds__(256) void k_build(const float* __restrict__ x,
                                               const float* __restrict__ proto,
                                               float* __restrict__ src) {
  const size_t total = (size_t)BN * SN * FD;
  for (size_t idx = (size_t)blockIdx.x * 256 + threadIdx.x; idx < total;
       idx += (size_t)gridDim.x * 256) {
    size_t rem = idx;
    const int f = (int)(rem % FD); rem /= FD;
    const int s = (int)(rem % SN); rem /= SN;
    const int b = (int)rem;
    // torch view: prototypes (C,1,F) flat reinterpreted as (F,C)
    src[idx] = (s < TN) ? x[((size_t)b * TN + s) * FD + f]
                        : proto[(size_t)f * CP + (s - TN)];
  }
}

// ---------------- generic GEMM: C[m,n] = sum_k A[m,k]*Wval(n,k) + bias -----
// WT=false: Wval(n,k) = W[n*K+k]   (weights stored (N,K), i.e. A @ W^T)
// WT=true : Wval(n,k) = W[k*N+n]   (plain A @ W, used for W_eff = Win @ wconv)
// Tile 128x128, 8x8 per thread, K-step 16.  Requires N%128==0, K%16==0.
template <bool RELU, bool WT>
__global__ __launch_bounds__(256) void k_gemm(const float* __restrict__ A,
                                              const float* __restrict__ W,
                                              const float* __restrict__ bias,
                                              float* __restrict__ Cm,
                                              int M, int N, int K) {
  __shared__ float As[16][132];
  __shared__ float Ws[16][132];
  const int tid = threadIdx.x;
  const int tx = tid & 15;   // n
  const int ty = tid >> 4;   // m
  const int m0 = blockIdx.y * 128, n0 = blockIdx.x * 128;
  float acc[8][8];
#pragma unroll
  for (int i = 0; i < 8; ++i)
#pragma unroll
    for (int j = 0; j < 8; ++j) acc[i][j] = 0.f;

  for (int k0 = 0; k0 < K; k0 += 16) {
#pragma unroll
    for (int l = 0; l < 8; ++l) {  // A tile 128m x 16k
      const int idx = tid + l * 256;
      const int mm = idx >> 4, kk = idx & 15;
      const int gm = m0 + mm;
      As[kk][mm] = (gm < M) ? A[(size_t)gm * K + k0 + kk] : 0.f;
    }
    if (WT) {
#pragma unroll
      for (int l = 0; l < 8; ++l) {  // 16k x 128n, contiguous in n
        const int idx = tid + l * 256;
        const int kk = idx >> 7, nn = idx & 127;
        Ws[kk][nn] = W[(size_t)(k0 + kk) * N + n0 + nn];
      }
    } else {
#pragma unroll
      for (int l = 0; l < 8; ++l) {  // 128n x 16k
        const int idx = tid + l * 256;
        const int nn = idx >> 4, kk = idx & 15;
        Ws[kk][nn] = W[(size_t)(n0 + nn) * K + k0 + kk];
      }
    }
    __syncthreads();
#pragma unroll
    for (int kk = 0; kk < 16; ++kk) {
      const float4 a0 = *(const float4*)&As[kk][ty * 8];
      const float4 a1 = *(const float4*)&As[kk][ty * 8 + 4];
      const float4 w0 = *(const float4*)&Ws[kk][tx * 8];
      const float4 w1 = *(const float4*)&Ws[kk][tx * 8 + 4];
      const float a[8] = {a0.x, a0.y, a0.z, a0.w, a1.x, a1.y, a1.z, a1.w};
      const float w[8] = {w0.x, w0.y, w0.z, w0.w, w1.x, w1.y, w1.z, w1.w};
#pragma unroll
      for (int i = 0; i < 8; ++i)
#pragma unroll
        for (int j = 0; j < 8; ++j) acc[i][j] += a[i] * w[j];
    }
    __syncthreads();
  }
#pragma unroll
  for (int i = 0; i < 8; ++i) {
    const int gm = m0 + ty * 8 + i;
    if (gm >= M) continue;
#pragma unroll
    for (int j = 0; j < 8; ++j) {
      const int gn = n0 + tx * 8 + j;
      float v = acc[i][j];
      if (bias) v += bias[gn];
      if (RELU) v = fmaxf(v, 0.f);
      Cm[(size_t)gm * N + gn] = v;
    }
  }
}

// ---------------- effective bias: beff[n] = binp[n] + Win[n,:]·bvec --------
__global__ __launch_bounds__(256) void k_beff(const float* __restrict__ Win,
                                              const float* __restrict__ bvec,
                                              const float* __restrict__ binp,
                                              float* __restrict__ beff) {
  const int n = blockIdx.x;
  const int tid = threadIdx.x;
  float s = 0.f;
  for (int j = tid; j < FD; j += 256) s += Win[(size_t)n * FD + j] * bvec[j];
  __shared__ float red[4];
#pragma unroll
  for (int o = 32; o; o >>= 1) s += __shfl_xor(s, o);
  if ((tid & 63) == 0) red[tid >> 6] = s;
  __syncthreads();
  if (tid == 0) beff[n] = red[0] + red[1] + red[2] + red[3] + binp[n];
}

// ---------------- flash attention, BQ=BK=32, dh=128 ------------------------
// grid: (ceil(S/32), H, B); 256 threads; thread owns (qr = tid>>3, 16 d-cols)
constexpr int LDH = 132;  // DH + 4 pad: conflict-mitigating, 16B aligned
__global__ __launch_bounds__(256) void k_attn(const float* __restrict__ Qg,
                                              const float* __restrict__ Kg,
                                              const float* __restrict__ Vg,
                                              float* __restrict__ Og) {
  __shared__ float Qs[32][LDH];
  __shared__ float Ks[32][LDH];
  __shared__ float Vs[32][LDH];
  __shared__ float Ps[32][33];
  const int tid = threadIdx.x;
  const int b = blockIdx.z, h = blockIdx.y;
  const int q0 = blockIdx.x * 32;
  const size_t rowBase = (size_t)b * SN;
  const int hoff = h * DH;

  for (int idx = tid; idx < 32 * DH; idx += 256) {
    const int r = idx >> 7, c = idx & 127;
    const int gq = q0 + r;
    Qs[r][c] = (gq < SN) ? Qg[(rowBase + gq) * FD + hoff + c] : 0.f;
  }
  const int qr = tid >> 3;  // q-row 0..31
  const int kg = tid & 7;   // 4 k-rows / 16 d-cols group
  float m_run = -3.0e38f, l_run = 0.f;
  float4 o0{0.f, 0.f, 0.f, 0.f}, o1 = o0, o2 = o0, o3 = o0;
  __syncthreads();

  for (int k0 = 0; k0 < SN; k0 += 32) {
    for (int idx = tid; idx < 32 * DH; idx += 256) {
      const int r = idx >> 7, c = idx & 127;
      const int gk = k0 + r;
      float kv = 0.f, vv = 0.f;
      if (gk < SN) {
        const size_t g = (rowBase + gk) * FD + hoff + c;
        kv = Kg[g];
        vv = Vg[g];
      }
      Ks[r][c] = kv;
      Vs[r][c] = vv;
    }
    __syncthreads();

    const float4* qp = (const float4*)&Qs[qr][0];
    const float4* kp0 = (const float4*)&Ks[kg * 4 + 0][0];
    const float4* kp1 = (const float4*)&Ks[kg * 4 + 1][0];
    const float4* kp2 = (const float4*)&Ks[kg * 4 + 2][0];
    const float4* kp3 = (const float4*)&Ks[kg * 4 + 3][0];
    float d0 = 0.f, d1 = 0.f, d2 = 0.f, d3 = 0.f;
#pragma unroll 8
    for (int c4 = 0; c4 < DH / 4; ++c4) {
      const float4 q = qp[c4];
      const float4 ka = kp0[c4], kb = kp1[c4], kc = kp2[c4], kd = kp3[c4];
      d0 += q.x * ka.x + q.y * ka.y + q.z * ka.z + q.w * ka.w;
      d1 += q.x * kb.x + q.y * kb.y + q.z * kb.z + q.w * kb.w;
      d2 += q.x * kc.x + q.y * kc.y + q.z * kc.z + q.w * kc.w;
      d3 += q.x * kd.x + q.y * kd.y + q.z * kd.z + q.w * kd.w;
    }
    const float s0 = (k0 + kg * 4 + 0 < SN) ? d0 * SCALE : -3.0e38f;
    const float s1 = (k0 + kg * 4 + 1 < SN) ? d1 * SCALE : -3.0e38f;
    const float s2 = (k0 + kg * 4 + 2 < SN) ? d2 * SCALE : -3.0e38f;
    const float s3 = (k0 + kg * 4 + 3 < SN) ? d3 * SCALE : -3.0e38f;

    float mx = fmaxf(fmaxf(s0, s1), fmaxf(s2, s3));
    mx = fmaxf(mx, __shfl_xor(mx, 1, 8));
    mx = fmaxf(mx, __shfl_xor(mx, 2, 8));
    mx = fmaxf(mx, __shfl_xor(mx, 4, 8));
    const float m_new = fmaxf(m_run, mx);
    const float alpha = __expf(m_run - m_new);
    const float p0 = __expf(s0 - m_new), p1 = __expf(s1 - m_new);
    const float p2 = __expf(s2 - m_new), p3 = __expf(s3 - m_new);
    Ps[qr][kg * 4 + 0] = p0;
    Ps[qr][kg * 4 + 1] = p1;
    Ps[qr][kg * 4 + 2] = p2;
    Ps[qr][kg * 4 + 3] = p3;
    float ps = p0 + p1 + p2 + p3;
    ps += __shfl_xor(ps, 1, 8);
    ps += __shfl_xor(ps, 2, 8);
    ps += __shfl_xor(ps, 4, 8);
    l_run = l_run * alpha + ps;
    m_run = m_new;
    o0.x *= alpha; o0.y *= alpha; o0.z *= alpha; o0.w *= alpha;
    o1.x *= alpha; o1.y *= alpha; o1.z *= alpha; o1.w *= alpha;
    o2.x *= alpha; o2.y *= alpha; o2.z *= alpha; o2.w *= alpha;
    o3.x *= alpha; o3.y *= alpha; o3.z *= alpha; o3.w *= alpha;
    __syncthreads();  // Ps visible; Ks reads complete

#pragma unroll 4
    for (int kr = 0; kr < 32; ++kr) {
      const float p = Ps[qr][kr];
      const float4* vp = (const float4*)&Vs[kr][0];
      const float4 v0 = vp[kg * 4 + 0], v1 = vp[kg * 4 + 1];
      const float4 v2 = vp[kg * 4 + 2], v3 = vp[kg * 4 + 3];
      o0.x += p * v0.x; o0.y += p * v0.y; o0.z += p * v0.z; o0.w += p * v0.w;
      o1.x += p * v1.x; o1.y += p * v1.y; o1.z += p * v1.z; o1.w += p * v1.w;
      o2.x += p * v2.x; o2.y += p * v2.y; o2.z += p * v2.z; o2.w += p * v2.w;
      o3.x += p * v3.x; o3.y += p * v3.y; o3.z += p * v3.z; o3.w += p * v3.w;
    }
    __syncthreads();  // Vs/Ps reads complete before next tile load
  }

  const int gq = q0 + qr;
  if (gq < SN) {
    const float inv = 1.f / l_run;
    float4* dst = (float4*)&Og[(rowBase + gq) * FD + hoff + kg * 16];
    dst[0] = float4{o0.x * inv, o0.y * inv, o0.z * inv, o0.w * inv};
    dst[1] = float4{o1.x * inv, o1.y * inv, o1.z * inv, o1.w * inv};
    dst[2] = float4{o2.x * inv, o2.y * inv, o2.z * inv, o2.w * inv};
    dst[3] = float4{o3.x * inv, o3.y * inv, o3.z * inv, o3.w * inv};
  }
}

// ---------------- fused residual + LayerNorm (row = 1024) ------------------
__global__ __launch_bounds__(256) void k_add_ln(float* __restrict__ s,
                                                const float* __restrict__ d,
                                                const float* __restrict__ g,
                                                const float* __restrict__ be) {
  __shared__ float red[4];
  const int row = blockIdx.x;
  const size_t off = (size_t)row * FD;
  const int tid = threadIdx.x;
  float v[4];
  float sum = 0.f;
#pragma unroll
  for (int i = 0; i < 4; ++i) {
    const int c = tid + 256 * i;
    v[i] = s[off + c] + d[off + c];
    sum += v[i];
  }
#pragma unroll
  for (int o = 32; o; o >>= 1) sum += __shfl_xor(sum, o);
  if ((tid & 63) == 0) red[tid >> 6] = sum;
  __syncthreads();
  sum = red[0] + red[1] + red[2] + red[3];
  const float mu = sum * (1.f / FD);
  float vs = 0.f;
#pragma unroll
  for (int i = 0; i < 4; ++i) {
    const float t = v[i] - mu;
    vs += t * t;
  }
  __syncthreads();
#pragma unroll
  for (int o = 32; o; o >>= 1) vs += __shfl_xor(vs, o);
  if ((tid & 63) == 0) red[tid >> 6] = vs;
  __syncthreads();
  vs = red[0] + red[1] + red[2] + red[3];
  const float rstd = rsqrtf(vs * (1.f / FD) + 1e-5f);
#pragma unroll
  for (int i = 0; i < 4; ++i) {
    const int c = tid + 256 * i;
    s[off + c] = (v[i] - mu) * rstd * g[c] + be[c];
  }
}

// ---------------- Conv1d(F,F,k=3,pad=1) + bias + ReLU ----------------------
// out[b,o,t] = relu(bc[o] + sum_{i,k} src[b,t+k-1,i] * Wc[o,i,k])
// tile: 64 t x 64 o per block, 4x4 per thread, i-chunks of 16.
__global__ __launch_bounds__(256) void k_conv(const float* __restrict__ src,
                                              const float* __restrict__ Wc,
                                              const float* __restrict__ bc,
                                              float* __restrict__ y) {
  __shared__ float Ss[16][66];   // [i][t-row], rows t0-1 .. t0+64
  __shared__ float Ws[48][65];   // [(i%16)*3+k][o]
  const int tid = threadIdx.x;
  const int tx = tid & 15, ty = tid >> 4;
  const int t0 = blockIdx.x * 64, o0 = blockIdx.y * 64, b = blockIdx.z;
  const size_t sbase = (size_t)b * SN * FD;
  float acc[4][4];
#pragma unroll
  for (int i = 0; i < 4; ++i)
#pragma unroll
    for (int j = 0; j < 4; ++j) acc[i][j] = 0.f;

  for (int i0 = 0; i0 < FD; i0 += 16) {
    for (int idx = tid; idx < 66 * 16; idx += 256) {
      const int row = idx >> 4, ii = idx & 15;
      const int t = t0 - 1 + row;
      Ss[ii][row] =
          (t >= 0 && t < TN) ? src[sbase + (size_t)t * FD + i0 + ii] : 0.f;
    }
    for (int idx = tid; idx < 64 * 48; idx += 256) {
      const int oo = idx / 48, r = idx % 48;  // r = (i-i0)*3 + k, contiguous
      Ws[r][oo] = Wc[(size_t)(o0 + oo) * (FD * 3) + i0 * 3 + r];
    }
    __syncthreads();
#pragma unroll
    for (int ii = 0; ii < 16; ++ii) {
      float a[6];
#pragma unroll
      for (int r = 0; r < 6; ++r) a[r] = Ss[ii][ty * 4 + r];
#pragma unroll
      for (int j = 0; j < 4; ++j) {
        const float w0 = Ws[ii * 3 + 0][tx * 4 + j];
        const float w1 = Ws[ii * 3 + 1][tx * 4 + j];
        const float w2 = Ws[ii * 3 + 2][tx * 4 + j];
#pragma unroll
        for (int i = 0; i < 4; ++i)
          acc[i][j] += a[i] * w0 + a[i + 1] * w1 + a[i + 2] * w2;
      }
    }
    __syncthreads();
  }
#pragma unroll
  for (int j = 0; j < 4; ++j) {
    const int o = o0 + tx * 4 + j;
    const float bias = bc[o];
#pragma unroll
    for (int i = 0; i < 4; ++i) {
      const int t = t0 + ty * 4 + i;
      y[((size_t)b * FD + o) * TN + t] = fmaxf(acc[i][j] + bias, 0.f);
    }
  }
}

// ---------------------------------------------------------------------------
extern "C" void kernel_launch(void* const* d_in, const int* in_sizes, int n_in,
                              void* d_out, int out_size, void* d_ws,
                              size_t ws_size, hipStream_t stream) {
  const float* x      = (const float*)d_in[0];
  const float* proto  = (const float*)d_in[1];
  const float* wq     = (const float*)d_in[2];
  const float* bq     = (const float*)d_in[3];
  const float* wk     = (const float*)d_in[4];
  const float* bk     = (const float*)d_in[5];
  const float* in_w   = (const float*)d_in[6];
  const float* in_b   = (const float*)d_in[7];
  const float* out_w  = (const float*)d_in[8];
  const float* out_b  = (const float*)d_in[9];
  const float* l1_w   = (const float*)d_in[10];
  const float* l1_b   = (const float*)d_in[11];
  const float* l2_w   = (const float*)d_in[12];
  const float* l2_b   = (const float*)d_in[13];
  const float* ln1_g  = (const float*)d_in[14];
  const float* ln1_b  = (const float*)d_in[15];
  const float* ln2_g  = (const float*)d_in[16];
  const float* ln2_b  = (const float*)d_in[17];
  const float* emb_w  = (const float*)d_in[18];
  const float* emb_b  = (const float*)d_in[19];

  float* ws = (float*)d_ws;
  const size_t MF = (size_t)MR * FD;
  float* src = ws;
  float* bQ  = ws + 1 * MF;
  float* bK  = ws + 2 * MF;
  float* bV  = ws + 3 * MF;
  float* bO  = ws + 4 * MF;
  float* bFF = ws + 5 * MF;                       // MR * DF
  float* wEq = bFF + (size_t)MR * DF;             // F*F
  float* wEk = wEq + (size_t)FD * FD;             // F*F
  float* beq = wEk + (size_t)FD * FD;             // F
  float* bek = beq + FD;                          // F

  k_build<<<2048, 256, 0, stream>>>(x, proto, src);

  for (int l = 0; l < 2; ++l) {
    const float* wq_l   = wq + (size_t)l * FD * FD;
    const float* bq_l   = bq + (size_t)l * FD;
    const float* wk_l   = wk + (size_t)l * FD * FD;
    const float* bk_l   = bk + (size_t)l * FD;
    const float* in_w_l = in_w + (size_t)l * 3 * FD * FD;
    const float* in_b_l = in_b + (size_t)l * 3 * FD;
    const float* ow_l   = out_w + (size_t)l * FD * FD;
    const float* ob_l   = out_b + (size_t)l * FD;
    const float* l1w_l  = l1_w + (size_t)l * DF * FD;
    const float* l1b_l  = l1_b + (size_t)l * DF;
    const float* l2w_l  = l2_w + (size_t)l * FD * DF;
    const float* l2b_l  = l2_b + (size_t)l * FD;

    // effective QK projections: W_eff = W_in @ w_conv ; b_eff = W_in·b + b_in
    dim3 ge(FD / 128, FD / 128);
    k_gemm<false, true><<<ge, 256, 0, stream>>>(in_w_l, wq_l, nullptr, wEq,
                                                FD, FD, FD);
    k_gemm<false, true><<<ge, 256, 0, stream>>>(in_w_l + (size_t)FD * FD, wk_l,
                                                nullptr, wEk, FD, FD, FD);
    k_beff<<<FD, 256, 0, stream>>>(in_w_l, bq_l, in_b_l, beq);
    k_beff<<<FD, 256, 0, stream>>>(in_w_l + (size_t)FD * FD, bk_l,
                                   in_b_l + FD, bek);

    dim3 gg(FD / 128, (MR + 127) / 128);
    k_gemm<false, false><<<gg, 256, 0, stream>>>(src, wEq, beq, bQ, MR, FD, FD);
    k_gemm<false, false><<<gg, 256, 0, stream>>>(src, wEk, bek, bK, MR, FD, FD);
    k_gemm<false, false><<<gg, 256, 0, stream>>>(
        src, in_w_l + (size_t)2 * FD * FD, in_b_l + 2 * FD, bV, MR, FD, FD);

    dim3 ga((SN + 31) / 32, HN, BN);
    k_attn<<<ga, 256, 0, stream>>>(bQ, bK, bV, bO);

    k_gemm<false, false><<<gg, 256, 0, stream>>>(bO, ow_l, ob_l, bQ, MR, FD, FD);
    k_add_ln<<<MR, 256, 0, stream>>>(src, bQ, ln1_g + (size_t)l * FD,
                                     ln1_b + (size_t)l * FD);

    dim3 gf(DF / 128, (MR + 127) / 128);
    k_gemm<true, false><<<gf, 256, 0, stream>>>(src, l1w_l, l1b_l, bFF, MR, DF,
                                                FD);
    k_gemm<false, false><<<gg, 256, 0, stream>>>(bFF, l2w_l, l2b_l, bQ, MR, FD,
                                                 DF);
    k_add_ln<<<MR, 256, 0, stream>>>(src, bQ, ln2_g + (size_t)l * FD,
                                     ln2_b + (size_t)l * FD);
  }

  dim3 gc(TN / 64, FD / 64, BN);
  k_conv<<<gc, 256, 0, stream>>>(src, emb_w, emb_b, (float*)d_out);
}

// Round 2
// 1224.092 us; speedup vs baseline: 12.6262x; 12.6262x over previous
//
#include <hip/hip_runtime.h>
#include <hip/hip_bf16.h>

// ---------------------------------------------------------------------------
// Round 2: bf16 MFMA everywhere.
//  - k_mm: m97-structure GEMM (128x128 tile, BK=32, global_load_lds w16)
//  - k_fattn: flash attention, swapped QK^T (S^T), XOR-swizzled K/Vt LDS
//  - conv as 3-tap K=3072 GEMM over zero-padded src
// ---------------------------------------------------------------------------

constexpr int BN = 4, TN = 2048, FD = 1024, CP = 200, SN = TN + CP;  // 2248
constexpr int HN = 8, DH = 128, DF = 128, MR = BN * SN;              // 8992
constexpr float SCALE = 0.08838834764831845f;  // 1/sqrt(128)

typedef __attribute__((ext_vector_type(8))) short short8;
typedef __attribute__((ext_vector_type(4))) float f32x4;

__device__ __forceinline__ ushort f2b(float f) {
  union { float f; uint u; } v{f};
  return (ushort)((v.u + 0x7fffu + ((v.u >> 16) & 1u)) >> 16);
}
__device__ __forceinline__ void gld16(const void* g, void* l) {
  __builtin_amdgcn_global_load_lds(
      (const __attribute__((address_space(1))) void*)g,
      (__attribute__((address_space(3))) void*)l, 16, 0, 0);
}

// ---------------- build src fp32 + bf16 mirror -----------------------------
__global__ __launch_bounds__(256) void k_build(const float* __restrict__ x,
                                               const float* __restrict__ proto,
                                               float* __restrict__ src,
                                               ushort* __restrict__ srcb) {
  const size_t total = (size_t)BN * SN * FD;
  for (size_t idx = (size_t)blockIdx.x * 256 + threadIdx.x; idx < total;
       idx += (size_t)gridDim.x * 256) {
    size_t rem = idx;
    const int f = (int)(rem % FD); rem /= FD;
    const int s = (int)(rem % SN); rem /= SN;
    const int b = (int)rem;
    const float v = (s < TN) ? x[((size_t)b * TN + s) * FD + f]
                             : proto[(size_t)f * CP + (s - TN)];
    src[idx] = v;
    srcb[idx] = f2b(v);
  }
}

// ---------------- flat fp32 -> bf16 ----------------------------------------
__global__ __launch_bounds__(256) void k_cvt(const float* __restrict__ in,
                                             ushort* __restrict__ out, int n) {
  for (int i = blockIdx.x * 256 + threadIdx.x; i < n; i += gridDim.x * 256)
    out[i] = f2b(in[i]);
}

// ---------------- transpose-convert FxF fp32 -> bf16 (WT[n][k]=W[k][n]) ----
__global__ __launch_bounds__(256) void k_cvtT(const float* __restrict__ W,
                                              ushort* __restrict__ WT) {
  __shared__ float t[32][33];
  const int tx = threadIdx.x & 31, ty = threadIdx.x >> 5;
  const int x0 = blockIdx.x * 32, y0 = blockIdx.y * 32;
#pragma unroll
  for (int dy = 0; dy < 4; ++dy)
    t[ty + dy * 8][tx] = W[(size_t)(y0 + ty + dy * 8) * FD + x0 + tx];
  __syncthreads();
#pragma unroll
  for (int dy = 0; dy < 4; ++dy)
    WT[(size_t)(x0 + ty + dy * 8) * FD + y0 + tx] = f2b(t[tx][ty + dy * 8]);
}

// ---------------- per-(b,h) transpose V (S x DH) -> Vt (DH x S) ------------
__global__ __launch_bounds__(256) void k_vT(const ushort* __restrict__ V,
                                            ushort* __restrict__ Vt) {
  __shared__ ushort t[32][34];
  const int tx = threadIdx.x & 31, ty = threadIdx.x >> 5;
  const int s0 = blockIdx.x * 32, d0 = blockIdx.y * 32, bh = blockIdx.z;
  const int b = bh >> 3, h = bh & 7;
#pragma unroll
  for (int dy = 0; dy < 4; ++dy) {
    const int s = min(s0 + ty + dy * 8, SN - 1);
    t[ty + dy * 8][tx] = V[((size_t)b * SN + s) * FD + h * DH + d0 + tx];
  }
  __syncthreads();
#pragma unroll
  for (int dy = 0; dy < 4; ++dy) {
    const int s = s0 + tx;
    if (s < SN)
      Vt[((size_t)bh * DH + d0 + ty + dy * 8) * SN + s] = t[tx][ty + dy * 8];
  }
}

// ---------------- conv weight repack: cw[o][tau*F+i] = W[o][i][tau] --------
__global__ __launch_bounds__(256) void k_convw(const float* __restrict__ W,
                                               ushort* __restrict__ out) {
  const int n = FD * FD * 3;
  for (int idx = blockIdx.x * 256 + threadIdx.x; idx < n;
       idx += gridDim.x * 256) {
    const int o = idx / (FD * 3);
    const int rem = idx % (FD * 3);
    const int tau = rem >> 10, i = rem & 1023;
    out[idx] = f2b(W[(size_t)o * (FD * 3) + i * 3 + tau]);
  }
}

// ---------------- zero-padded bf16 src for conv ----------------------------
__global__ __launch_bounds__(256) void k_pad(const ushort* __restrict__ sb,
                                             ushort* __restrict__ pad) {
  const int n = BN * (TN + 2) * FD;
  for (int idx = blockIdx.x * 256 + threadIdx.x; idx < n;
       idx += gridDim.x * 256) {
    const int f = idx & 1023;
    const int rem = idx >> 10;
    const int r = rem % (TN + 2), b = rem / (TN + 2);
    ushort v = 0;
    if (r >= 1 && r <= TN) v = sb[((size_t)b * SN + (r - 1)) * FD + f];
    pad[idx] = v;
  }
}

// ---------------- effective bias: beff[n] = binp[n] + Win[n,:]·bvec --------
__global__ __launch_bounds__(256) void k_beff(const float* __restrict__ Win,
                                              const float* __restrict__ bvec,
                                              const float* __restrict__ binp,
                                              float* __restrict__ beff) {
  const int n = blockIdx.x;
  const int tid = threadIdx.x;
  float s = 0.f;
  for (int j = tid; j < FD; j += 256) s += Win[(size_t)n * FD + j] * bvec[j];
  __shared__ float red[4];
#pragma unroll
  for (int o = 32; o; o >>= 1) s += __shfl_xor(s, o);
  if ((tid & 63) == 0) red[tid >> 6] = s;
  __syncthreads();
  if (tid == 0) beff[n] = red[0] + red[1] + red[2] + red[3] + binp[n];
}

// ---------------- bf16 MFMA GEMM: C[m,n] = sum_k A[m,k]*W[n,k] + bias ------
// 128x128 tile, BK=32, 4 waves (64x64 quadrant each, 4x4 frags 16x16x32).
template <bool RELU, bool BF16OUT>
__global__ __launch_bounds__(256) void k_mm(const ushort* __restrict__ A,
                                            const ushort* __restrict__ W,
                                            const float* __restrict__ bias,
                                            void* __restrict__ Cv,
                                            int M, int N, int K) {
  __shared__ __align__(16) ushort As[128 * 32];
  __shared__ __align__(16) ushort Ws[128 * 32];
  const int tid = threadIdx.x;
  const int lane = tid & 63, wv = tid >> 6;
  const int l15 = lane & 15, g = lane >> 4;
  const int wr = wv >> 1, wc = wv & 1;
  const int m0 = blockIdx.y * 128, n0 = blockIdx.x * 128;
  f32x4 acc[4][4];
#pragma unroll
  for (int i = 0; i < 4; ++i)
#pragma unroll
    for (int j = 0; j < 4; ++j) acc[i][j] = (f32x4){0.f, 0.f, 0.f, 0.f};

  for (int k0 = 0; k0 < K; k0 += 32) {
#pragma unroll
    for (int j = 0; j < 2; ++j) {  // A tile: 128x32 = 512 slots of 8 bf16
      const int u = j * 256 + wv * 64 + lane;
      const int r = u >> 2, c = (u & 3) * 8;
      const int gm = min(m0 + r, M - 1);
      gld16(A + (size_t)gm * K + k0 + c, As + (size_t)u * 8);
    }
#pragma unroll
    for (int j = 0; j < 2; ++j) {  // W tile
      const int u = j * 256 + wv * 64 + lane;
      const int r = u >> 2, c = (u & 3) * 8;
      gld16(W + (size_t)(n0 + r) * K + k0 + c, Ws + (size_t)u * 8);
    }
    __syncthreads();
    short8 af[4], bfr[4];
#pragma unroll
    for (int i = 0; i < 4; ++i)
      af[i] = *(const short8*)(As + (wr * 64 + i * 16 + l15) * 32 + g * 8);
#pragma unroll
    for (int j = 0; j < 4; ++j)
      bfr[j] = *(const short8*)(Ws + (wc * 64 + j * 16 + l15) * 32 + g * 8);
#pragma unroll
    for (int i = 0; i < 4; ++i)
#pragma unroll
      for (int j = 0; j < 4; ++j)
        acc[i][j] = __builtin_amdgcn_mfma_f32_16x16x32_bf16(af[i], bfr[j],
                                                            acc[i][j], 0, 0, 0);
    __syncthreads();
  }
#pragma unroll
  for (int i = 0; i < 4; ++i) {
#pragma unroll
    for (int r = 0; r < 4; ++r) {
      const int row = m0 + wr * 64 + i * 16 + g * 4 + r;
      if (row >= M) continue;
#pragma unroll
      for (int j = 0; j < 4; ++j) {
        const int col = n0 + wc * 64 + j * 16 + l15;
        float v = acc[i][j][r];
        if (bias) v += bias[col];
        if (RELU) v = fmaxf(v, 0.f);
        if (BF16OUT)
          ((ushort*)Cv)[(size_t)row * N + col] = f2b(v);
        else
          ((float*)Cv)[(size_t)row * N + col] = v;
      }
    }
  }
}

// ---------------- conv as GEMM: M=B*TN rows, K=3*FD, shifted A rows --------
__global__ __launch_bounds__(256) void k_mmconv(const ushort* __restrict__ Ap,
                                                const ushort* __restrict__ W,
                                                const float* __restrict__ bias,
                                                float* __restrict__ Y) {
  constexpr int K = 3 * FD, N = FD;
  __shared__ __align__(16) ushort As[128 * 32];
  __shared__ __align__(16) ushort Ws[128 * 32];
  const int tid = threadIdx.x;
  const int lane = tid & 63, wv = tid >> 6;
  const int l15 = lane & 15, g = lane >> 4;
  const int wr = wv >> 1, wc = wv & 1;
  const int m0 = blockIdx.y * 128, n0 = blockIdx.x * 128;
  f32x4 acc[4][4];
#pragma unroll
  for (int i = 0; i < 4; ++i)
#pragma unroll
    for (int j = 0; j < 4; ++j) acc[i][j] = (f32x4){0.f, 0.f, 0.f, 0.f};

  for (int k0 = 0; k0 < K; k0 += 32) {
    const int tau = k0 >> 10;
    const int i0 = k0 & 1023;
#pragma unroll
    for (int j = 0; j < 2; ++j) {
      const int u = j * 256 + wv * 64 + lane;
      const int r = u >> 2, c = (u & 3) * 8;
      const int rm = m0 + r;
      const int b = rm >> 11, t = rm & 2047;
      gld16(Ap + ((size_t)(b * (TN + 2) + t + tau) * FD + i0 + c),
            As + (size_t)u * 8);
    }
#pragma unroll
    for (int j = 0; j < 2; ++j) {
      const int u = j * 256 + wv * 64 + lane;
      const int r = u >> 2, c = (u & 3) * 8;
      gld16(W + (size_t)(n0 + r) * K + k0 + c, Ws + (size_t)u * 8);
    }
    __syncthreads();
    short8 af[4], bfr[4];
#pragma unroll
    for (int i = 0; i < 4; ++i)
      af[i] = *(const short8*)(As + (wr * 64 + i * 16 + l15) * 32 + g * 8);
#pragma unroll
    for (int j = 0; j < 4; ++j)
      bfr[j] = *(const short8*)(Ws + (wc * 64 + j * 16 + l15) * 32 + g * 8);
#pragma unroll
    for (int i = 0; i < 4; ++i)
#pragma unroll
      for (int j = 0; j < 4; ++j)
        acc[i][j] = __builtin_amdgcn_mfma_f32_16x16x32_bf16(af[i], bfr[j],
                                                            acc[i][j], 0, 0, 0);
    __syncthreads();
  }
#pragma unroll
  for (int i = 0; i < 4; ++i) {
#pragma unroll
    for (int r = 0; r < 4; ++r) {
      const int rm = m0 + wr * 64 + i * 16 + g * 4 + r;
      const int b = rm >> 11, t = rm & 2047;
#pragma unroll
      for (int j = 0; j < 4; ++j) {
        const int col = n0 + wc * 64 + j * 16 + l15;
        const float v = fmaxf(acc[i][j][r] + bias[col], 0.f);
        Y[((size_t)(b * FD + col)) * TN + t] = v;
      }
    }
  }
}

// ---------------- flash attention: 4 waves x 16 q-rows, KVB=64 -------------
// Swapped QK^T: S^T = mfma(K, Q) -> lane holds q = lane&15 (softmax lane-local
// + shfl 16/32). P round-trips LDS (stride 144B). K tile [64][256B] and
// Vt tile [128][128B] staged via global_load_lds with slot-XOR swizzle.
__global__ __launch_bounds__(256) void k_fattn(const ushort* __restrict__ Qg,
                                               const ushort* __restrict__ Kg,
                                               const ushort* __restrict__ Vt,
                                               ushort* __restrict__ Og) {
  __shared__ __align__(16) ushort Ks[64 * 128];
  __shared__ __align__(16) ushort Vs[128 * 64];
  __shared__ __align__(16) ushort Ps[4][16 * 72];
  const int tid = threadIdx.x, lane = tid & 63, wv = tid >> 6;
  const int l15 = lane & 15, g = lane >> 4;
  const int b = blockIdx.z, h = blockIdx.y, q0 = blockIdx.x * 64;
  const size_t rowBase = (size_t)b * SN;
  const int hoff = h * DH;
  const size_t vbase = (size_t)(b * HN + h) * DH * SN;

  short8 qf[4];
  const int qrow = min(q0 + wv * 16 + l15, SN - 1);
#pragma unroll
  for (int c = 0; c < 4; ++c)
    qf[c] = *(const short8*)(Qg + (rowBase + qrow) * FD + hoff + c * 32 + g * 8);

  f32x4 o[8];
#pragma unroll
  for (int dt = 0; dt < 8; ++dt) o[dt] = (f32x4){0.f, 0.f, 0.f, 0.f};
  float m_run = -3.0e38f, l_run = 0.f;
  const char* KsB = (const char*)Ks;
  const char* VsB = (const char*)Vs;
  char* PsB = (char*)&Ps[wv][0];

  for (int kv0 = 0; kv0 < SN; kv0 += 64) {
    // stage K tile [64 rows][16 slots of 16B], slot s holds chunk s^(row&7)
#pragma unroll
    for (int j = 0; j < 4; ++j) {
      const int su = j * 256 + wv * 64 + lane;
      const int row = su >> 4, s = su & 15;
      const int c16 = s ^ (row & 7);
      const int krow = min(kv0 + row, SN - 1);
      gld16(Kg + (rowBase + krow) * FD + hoff + c16 * 8, Ks + (size_t)su * 8);
    }
    // stage Vt tile [128 rows][8 slots of 16B]
#pragma unroll
    for (int j = 0; j < 4; ++j) {
      const int su = j * 256 + wv * 64 + lane;
      const int row = su >> 3, s = su & 7;
      const int cc = s ^ (row & 7);
      const int kvc = min(kv0 + cc * 8, SN - 8);
      gld16(Vt + vbase + (size_t)row * SN + kvc, Vs + (size_t)su * 8);
    }
    __syncthreads();

    // S^T = K · Q^T  (4 kv-tiles of 16)
    f32x4 st[4];
#pragma unroll
    for (int kt = 0; kt < 4; ++kt) {
      f32x4 s4 = (f32x4){0.f, 0.f, 0.f, 0.f};
      const int row = kt * 16 + l15;
#pragma unroll
      for (int c = 0; c < 4; ++c) {
        const short8 kf = *(const short8*)(
            KsB + row * 256 + (((c * 4 + g) ^ (row & 7)) << 4));
        s4 = __builtin_amdgcn_mfma_f32_16x16x32_bf16(kf, qf[c], s4, 0, 0, 0);
      }
      st[kt] = s4;
    }

    // online softmax in q = l15 domain
    float p[16];
    float pm = -3.0e38f;
#pragma unroll
    for (int kt = 0; kt < 4; ++kt)
#pragma unroll
      for (int r = 0; r < 4; ++r) {
        const int kvg = kv0 + kt * 16 + g * 4 + r;
        const float sc = (kvg < SN) ? st[kt][r] * SCALE : -3.0e38f;
        p[kt * 4 + r] = sc;
        pm = fmaxf(pm, sc);
      }
    pm = fmaxf(pm, __shfl_xor(pm, 16));
    pm = fmaxf(pm, __shfl_xor(pm, 32));
    const float m_new = fmaxf(m_run, pm);
    const float alpha = __expf(m_run - m_new);
    float lsum = 0.f;
#pragma unroll
    for (int i = 0; i < 16; ++i) {
      p[i] = __expf(p[i] - m_new);
      lsum += p[i];
    }
    lsum += __shfl_xor(lsum, 16);
    lsum += __shfl_xor(lsum, 32);
    l_run = l_run * alpha + lsum;
    m_run = m_new;

    // write P (rows q=l15, cols kv), bf16, row stride 144B
#pragma unroll
    for (int kt = 0; kt < 4; ++kt) {
      const uint lo = (uint)f2b(p[kt * 4 + 0]) | ((uint)f2b(p[kt * 4 + 1]) << 16);
      const uint hi = (uint)f2b(p[kt * 4 + 2]) | ((uint)f2b(p[kt * 4 + 3]) << 16);
      *(uint2*)(PsB + l15 * 144 + kt * 32 + g * 8) = make_uint2(lo, hi);
    }

    // rescale O (o rows are q = g*4+r domain -> shuffle alpha over)
    float ar[4];
#pragma unroll
    for (int r = 0; r < 4; ++r) ar[r] = __shfl(alpha, g * 4 + r);
#pragma unroll
    for (int dt = 0; dt < 8; ++dt)
#pragma unroll
      for (int r = 0; r < 4; ++r) o[dt][r] *= ar[r];

    // PV: O += P · V
#pragma unroll
    for (int c2 = 0; c2 < 2; ++c2) {
      const short8 pf = *(const short8*)(PsB + l15 * 144 + c2 * 64 + g * 16);
#pragma unroll
      for (int dt = 0; dt < 8; ++dt) {
        const int row = dt * 16 + l15;
        const short8 vf = *(const short8*)(
            VsB + row * 128 + (((c2 * 4 + g) ^ (row & 7)) << 4));
        o[dt] = __builtin_amdgcn_mfma_f32_16x16x32_bf16(pf, vf, o[dt], 0, 0, 0);
      }
    }
    __syncthreads();
  }

  const float invl = 1.f / l_run;
  float ir[4];
#pragma unroll
  for (int r = 0; r < 4; ++r) ir[r] = __shfl(invl, g * 4 + r);
#pragma unroll
  for (int r = 0; r < 4; ++r) {
    const int orow = q0 + wv * 16 + g * 4 + r;
    if (orow >= SN) continue;
#pragma unroll
    for (int dt = 0; dt < 8; ++dt)
      Og[(rowBase + orow) * FD + hoff + dt * 16 + l15] = f2b(o[dt][r] * ir[r]);
  }
}

// ---------------- fused residual + LayerNorm (fp32 + bf16 mirror) ----------
__global__ __launch_bounds__(256) void k_add_ln(float* __restrict__ s,
                                                ushort* __restrict__ sb,
                                                const float* __restrict__ d,
                                                const float* __restrict__ g,
                                                const float* __restrict__ be) {
  __shared__ float red[4];
  const int row = blockIdx.x;
  const size_t off = (size_t)row * FD;
  const int tid = threadIdx.x;
  float v[4];
  float sum = 0.f;
#pragma unroll
  for (int i = 0; i < 4; ++i) {
    const int c = tid + 256 * i;
    v[i] = s[off + c] + d[off + c];
    sum += v[i];
  }
#pragma unroll
  for (int o = 32; o; o >>= 1) sum += __shfl_xor(sum, o);
  if ((tid & 63) == 0) red[tid >> 6] = sum;
  __syncthreads();
  sum = red[0] + red[1] + red[2] + red[3];
  const float mu = sum * (1.f / FD);
  float vs = 0.f;
#pragma unroll
  for (int i = 0; i < 4; ++i) {
    const float t = v[i] - mu;
    vs += t * t;
  }
  __syncthreads();
#pragma unroll
  for (int o = 32; o; o >>= 1) vs += __shfl_xor(vs, o);
  if ((tid & 63) == 0) red[tid >> 6] = vs;
  __syncthreads();
  vs = red[0] + red[1] + red[2] + red[3];
  const float rstd = rsqrtf(vs * (1.f / FD) + 1e-5f);
#pragma unroll
  for (int i = 0; i < 4; ++i) {
    const int c = tid + 256 * i;
    const float val = (v[i] - mu) * rstd * g[c] + be[c];
    s[off + c] = val;
    sb[off + c] = f2b(val);
  }
}

// ---------------------------------------------------------------------------
extern "C" void kernel_launch(void* const* d_in, const int* in_sizes, int n_in,
                              void* d_out, int out_size, void* d_ws,
                              size_t ws_size, hipStream_t stream) {
  const float* x      = (const float*)d_in[0];
  const float* proto  = (const float*)d_in[1];
  const float* wq     = (const float*)d_in[2];
  const float* bq     = (const float*)d_in[3];
  const float* wk     = (const float*)d_in[4];
  const float* bk     = (const float*)d_in[5];
  const float* in_w   = (const float*)d_in[6];
  const float* in_b   = (const float*)d_in[7];
  const float* out_w  = (const float*)d_in[8];
  const float* out_b  = (const float*)d_in[9];
  const float* l1_w   = (const float*)d_in[10];
  const float* l1_b   = (const float*)d_in[11];
  const float* l2_w   = (const float*)d_in[12];
  const float* l2_b   = (const float*)d_in[13];
  const float* ln1_g  = (const float*)d_in[14];
  const float* ln1_b  = (const float*)d_in[15];
  const float* ln2_g  = (const float*)d_in[16];
  const float* ln2_b  = (const float*)d_in[17];
  const float* emb_w  = (const float*)d_in[18];
  const float* emb_b  = (const float*)d_in[19];

  char* p = (char*)d_ws;
  auto take = [&](size_t bytes) {
    char* r = p;
    p += (bytes + 255) & ~(size_t)255;
    return r;
  };
  const size_t MF = (size_t)MR * FD;
  float*  src   = (float*)take(MF * 4);
  ushort* srcb  = (ushort*)take(MF * 2);
  ushort* bQ    = (ushort*)take(MF * 2);
  ushort* bK    = (ushort*)take(MF * 2);   // also fp32 aOut alias (w/ bV)
  ushort* bV    = (ushort*)take(MF * 2);
  ushort* bVt   = (ushort*)take((size_t)BN * HN * DH * SN * 2);
  ushort* bO    = (ushort*)take(MF * 2);
  ushort* bFF   = (ushort*)take((size_t)MR * DF * 2);
  ushort* wIn   = (ushort*)take((size_t)3 * FD * FD * 2);
  ushort* wOut  = (ushort*)take((size_t)FD * FD * 2);
  ushort* wL1   = (ushort*)take((size_t)DF * FD * 2);
  ushort* wL2   = (ushort*)take((size_t)FD * DF * 2);
  ushort* wqT   = (ushort*)take((size_t)FD * FD * 2);
  ushort* wkT   = (ushort*)take((size_t)FD * FD * 2);
  ushort* wEq   = (ushort*)take((size_t)FD * FD * 2);
  ushort* wEk   = (ushort*)take((size_t)FD * FD * 2);
  float*  beq   = (float*)take(FD * 4);
  float*  bek   = (float*)take(FD * 4);
  ushort* convW = (ushort*)take((size_t)FD * FD * 3 * 2);
  float*  aOut  = (float*)bK;    // 2 x 18.4MB contiguous
  ushort* srcPad = bQ;           // reused after attention is done

  k_build<<<2048, 256, 0, stream>>>(x, proto, src, srcb);

  for (int l = 0; l < 2; ++l) {
    const float* wq_l   = wq + (size_t)l * FD * FD;
    const float* bq_l   = bq + (size_t)l * FD;
    const float* wk_l   = wk + (size_t)l * FD * FD;
    const float* bk_l   = bk + (size_t)l * FD;
    const float* in_w_l = in_w + (size_t)l * 3 * FD * FD;
    const float* in_b_l = in_b + (size_t)l * 3 * FD;
    const float* ow_l   = out_w + (size_t)l * FD * FD;
    const float* ob_l   = out_b + (size_t)l * FD;
    const float* l1w_l  = l1_w + (size_t)l * DF * FD;
    const float* l1b_l  = l1_b + (size_t)l * DF;
    const float* l2w_l  = l2_w + (size_t)l * FD * DF;
    const float* l2b_l  = l2_b + (size_t)l * FD;

    k_cvt<<<2048, 256, 0, stream>>>(in_w_l, wIn, 3 * FD * FD);
    k_cvt<<<1024, 256, 0, stream>>>(ow_l, wOut, FD * FD);
    k_cvt<<<256, 256, 0, stream>>>(l1w_l, wL1, DF * FD);
    k_cvt<<<256, 256, 0, stream>>>(l2w_l, wL2, FD * DF);
    k_cvtT<<<dim3(32, 32), 256, 0, stream>>>(wq_l, wqT);
    k_cvtT<<<dim3(32, 32), 256, 0, stream>>>(wk_l, wkT);

    // W_eff = W_in[q/k] @ w_conv   -> bf16 (FxF)
    dim3 ge(FD / 128, FD / 128);
    k_mm<false, true><<<ge, 256, 0, stream>>>(wIn, wqT, nullptr, wEq, FD, FD, FD);
    k_mm<false, true><<<ge, 256, 0, stream>>>(wIn + (size_t)FD * FD, wkT,
                                              nullptr, wEk, FD, FD, FD);
    k_beff<<<FD, 256, 0, stream>>>(in_w_l, bq_l, in_b_l, beq);
    k_beff<<<FD, 256, 0, stream>>>(in_w_l + (size_t)FD * FD, bk_l,
                                   in_b_l + FD, bek);

    dim3 gg(FD / 128, (MR + 127) / 128);
    k_mm<false, true><<<gg, 256, 0, stream>>>(srcb, wEq, beq, bQ, MR, FD, FD);
    k_mm<false, true><<<gg, 256, 0, stream>>>(srcb, wEk, bek, bK, MR, FD, FD);
    k_mm<false, true><<<gg, 256, 0, stream>>>(srcb, wIn + (size_t)2 * FD * FD,
                                              in_b_l + 2 * FD, bV, MR, FD, FD);
    k_vT<<<dim3((SN + 31) / 32, DH / 32, BN * HN), 256, 0, stream>>>(bV, bVt);

    k_fattn<<<dim3((SN + 63) / 64, HN, BN), 256, 0, stream>>>(bQ, bK, bVt, bO);

    k_mm<false, false><<<gg, 256, 0, stream>>>(bO, wOut, ob_l, aOut, MR, FD, FD);
    k_add_ln<<<MR, 256, 0, stream>>>(src, srcb, aOut, ln1_g + (size_t)l * FD,
                                     ln1_b + (size_t)l * FD);

    dim3 gf(DF / 128, (MR + 127) / 128);
    k_mm<true, true><<<gf, 256, 0, stream>>>(srcb, wL1, l1b_l, bFF, MR, DF, FD);
    k_mm<false, false><<<gg, 256, 0, stream>>>(bFF, wL2, l2b_l, aOut, MR, FD, DF);
    k_add_ln<<<MR, 256, 0, stream>>>(src, srcb, aOut, ln2_g + (size_t)l * FD,
                                     ln2_b + (size_t)l * FD);
  }

  k_convw<<<1024, 256, 0, stream>>>(emb_w, convW);
  k_pad<<<2048, 256, 0, stream>>>(srcb, srcPad);
  k_mmconv<<<dim3(FD / 128, (BN * TN) / 128), 256, 0, stream>>>(
      srcPad, convW, emb_b, (float*)d_out);
}

// Round 3
// 1088.667 us; speedup vs baseline: 14.1969x; 1.1244x over previous
//
#include <hip/hip_runtime.h>
#include <hip/hip_bf16.h>

// ---------------------------------------------------------------------------
// Round 3: VALU-diet attention (exp2 fold, cvt_pk, defer-max, setprio,
// XOR-swizzled P), fused QKV GEMM (N=3072), XCD swizzle, hoisted weight prep.
// ---------------------------------------------------------------------------

constexpr int BN = 4, TN = 2048, FD = 1024, CP = 200, SN = TN + CP;  // 2248
constexpr int HN = 8, DH = 128, DF = 128, MR = BN * SN;              // 8992
constexpr int SF = 3 * FD;                                           // 3072
constexpr float C2 = 0.12751744f;  // (1/sqrt(128)) * log2(e)

typedef __attribute__((ext_vector_type(8))) short short8;
typedef __attribute__((ext_vector_type(4))) float f32x4;

__device__ __forceinline__ ushort f2b(float f) {
  union { float f; uint u; } v{f};
  return (ushort)((v.u + 0x7fffu + ((v.u >> 16) & 1u)) >> 16);
}
__device__ __forceinline__ uint cvt_pk_bf16(float a, float b) {
  uint r;
  asm("v_cvt_pk_bf16_f32 %0, %1, %2" : "=v"(r) : "v"(a), "v"(b));
  return r;
}
__device__ __forceinline__ float exp2_fast(float x) {
  float r;
  asm("v_exp_f32 %0, %1" : "=v"(r) : "v"(x));
  return r;
}
__device__ __forceinline__ void gld16(const void* g, void* l) {
  __builtin_amdgcn_global_load_lds(
      (const __attribute__((address_space(1))) void*)g,
      (__attribute__((address_space(3))) void*)l, 16, 0, 0);
}

// ---------------- build src fp32 + bf16 mirror (row/block) -----------------
__global__ __launch_bounds__(256) void k_build(const float* __restrict__ x,
                                               const float* __restrict__ proto,
                                               float* __restrict__ src,
                                               ushort* __restrict__ srcb) {
  const int row = blockIdx.x;  // 0..MR-1
  const int b = row / SN, s = row % SN;
  const int f = threadIdx.x * 4;
  const size_t o = (size_t)row * FD + f;
  float4 v;
  if (s < TN) {
    v = *(const float4*)(x + ((size_t)b * TN + s) * FD + f);
  } else {
    const int c = s - TN;
    v.x = proto[(size_t)(f + 0) * CP + c];
    v.y = proto[(size_t)(f + 1) * CP + c];
    v.z = proto[(size_t)(f + 2) * CP + c];
    v.w = proto[(size_t)(f + 3) * CP + c];
  }
  *(float4*)(src + o) = v;
  ushort4 u{f2b(v.x), f2b(v.y), f2b(v.z), f2b(v.w)};
  *(ushort4*)(srcb + o) = u;
}

// ---------------- flat fp32 -> bf16 (vec4) ---------------------------------
__global__ __launch_bounds__(256) void k_cvt(const float* __restrict__ in,
                                             ushort* __restrict__ out, int n) {
  const int n4 = n >> 2;
  for (int i = blockIdx.x * 256 + threadIdx.x; i < n4; i += gridDim.x * 256) {
    const float4 v = *(const float4*)(in + (size_t)i * 4);
    ushort4 u{f2b(v.x), f2b(v.y), f2b(v.z), f2b(v.w)};
    *(ushort4*)(out + (size_t)i * 4) = u;
  }
}

// ---------------- transpose-convert FxF fp32 -> bf16, z = layer ------------
__global__ __launch_bounds__(256) void k_cvtT(const float* __restrict__ Wg,
                                              ushort* __restrict__ WTg) {
  const float* W = Wg + (size_t)blockIdx.z * FD * FD;
  ushort* WT = WTg + (size_t)blockIdx.z * FD * FD;
  __shared__ float t[32][33];
  const int tx = threadIdx.x & 31, ty = threadIdx.x >> 5;
  const int x0 = blockIdx.x * 32, y0 = blockIdx.y * 32;
#pragma unroll
  for (int dy = 0; dy < 4; ++dy)
    t[ty + dy * 8][tx] = W[(size_t)(y0 + ty + dy * 8) * FD + x0 + tx];
  __syncthreads();
#pragma unroll
  for (int dy = 0; dy < 4; ++dy)
    WT[(size_t)(x0 + ty + dy * 8) * FD + y0 + tx] = f2b(t[tx][ty + dy * 8]);
}

// ---------------- per-(b,h) transpose V (from packed QKV) ------------------
__global__ __launch_bounds__(256) void k_vT(const ushort* __restrict__ V,
                                            ushort* __restrict__ Vt) {
  __shared__ ushort t[32][34];
  const int tx = threadIdx.x & 31, ty = threadIdx.x >> 5;
  const int s0 = blockIdx.x * 32, d0 = blockIdx.y * 32, bh = blockIdx.z;
  const int b = bh >> 3, h = bh & 7;
#pragma unroll
  for (int dy = 0; dy < 4; ++dy) {
    const int s = min(s0 + ty + dy * 8, SN - 1);
    t[ty + dy * 8][tx] = V[((size_t)b * SN + s) * SF + h * DH + d0 + tx];
  }
  __syncthreads();
#pragma unroll
  for (int dy = 0; dy < 4; ++dy) {
    const int s = s0 + tx;
    if (s < SN)
      Vt[((size_t)bh * DH + d0 + ty + dy * 8) * SN + s] = t[tx][ty + dy * 8];
  }
}

// ---------------- conv weight repack: cw[o][tau*F+i] = W[o][i][tau] --------
__global__ __launch_bounds__(256) void k_convw(const float* __restrict__ W,
                                               ushort* __restrict__ out) {
  const int n = FD * FD * 3;
  for (int idx = blockIdx.x * 256 + threadIdx.x; idx < n;
       idx += gridDim.x * 256) {
    const int o = idx / (FD * 3);
    const int rem = idx % (FD * 3);
    const int tau = rem >> 10, i = rem & 1023;
    out[idx] = f2b(W[(size_t)o * (FD * 3) + i * 3 + tau]);
  }
}

// ---------------- zero-padded bf16 src for conv (row/block) ----------------
__global__ __launch_bounds__(256) void k_pad(const ushort* __restrict__ sb,
                                             ushort* __restrict__ pad) {
  const int r = blockIdx.x, b = blockIdx.y;  // r in [0, TN+2)
  const int f = threadIdx.x * 4;
  ushort4 v{0, 0, 0, 0};
  if (r >= 1 && r <= TN)
    v = *(const ushort4*)(sb + ((size_t)b * SN + (r - 1)) * FD + f);
  *(ushort4*)(pad + ((size_t)b * (TN + 2) + r) * FD + f) = v;
}

// ---------------- effective bias, y = layer --------------------------------
__global__ __launch_bounds__(256) void k_beff(const float* __restrict__ in_w,
                                              const float* __restrict__ bvec,
                                              const float* __restrict__ in_b,
                                              float* __restrict__ out, int qk) {
  const int n = blockIdx.x, l = blockIdx.y, tid = threadIdx.x;
  const float* Win = in_w + (size_t)(l * 3 + qk) * FD * FD;
  const float* bv = bvec + (size_t)l * FD;
  float s = 0.f;
  for (int j = tid; j < FD; j += 256) s += Win[(size_t)n * FD + j] * bv[j];
  __shared__ float red[4];
#pragma unroll
  for (int o = 32; o; o >>= 1) s += __shfl_xor(s, o);
  if ((tid & 63) == 0) red[tid >> 6] = s;
  __syncthreads();
  if (tid == 0)
    out[l * 3 * FD + qk * FD + n] =
        red[0] + red[1] + red[2] + red[3] + in_b[l * 3 * FD + qk * FD + n];
}

// ---------------- copy V bias rows -----------------------------------------
__global__ __launch_bounds__(256) void k_copyv(const float* __restrict__ in_b,
                                               float* __restrict__ bqkv) {
  const int l = blockIdx.y;
  const int i = blockIdx.x * 256 + threadIdx.x;
  bqkv[l * 3 * FD + 2 * FD + i] = in_b[l * 3 * FD + 2 * FD + i];
}

// ---------------- bf16 MFMA GEMM (m97 structure + XCD swizzle) -------------
template <bool RELU, bool BF16OUT>
__global__ __launch_bounds__(256) void k_mm(const ushort* __restrict__ A,
                                            const ushort* __restrict__ W,
                                            const float* __restrict__ bias,
                                            void* __restrict__ Cv,
                                            int M, int N, int K) {
  __shared__ __align__(16) ushort As[128 * 32];
  __shared__ __align__(16) ushort Ws[128 * 32];
  const int tid = threadIdx.x;
  const int lane = tid & 63, wv = tid >> 6;
  const int l15 = lane & 15, g = lane >> 4;
  const int wr = wv >> 1, wc = wv & 1;
  int bx = blockIdx.x, by = blockIdx.y;
  const int nwg = gridDim.x * gridDim.y;
  if ((nwg & 7) == 0) {  // bijective XCD swizzle (T1)
    int bid = by * gridDim.x + bx;
    bid = (bid & 7) * (nwg >> 3) + (bid >> 3);
    bx = bid % gridDim.x;
    by = bid / gridDim.x;
  }
  const int m0 = by * 128, n0 = bx * 128;
  f32x4 acc[4][4];
#pragma unroll
  for (int i = 0; i < 4; ++i)
#pragma unroll
    for (int j = 0; j < 4; ++j) acc[i][j] = (f32x4){0.f, 0.f, 0.f, 0.f};

  for (int k0 = 0; k0 < K; k0 += 32) {
#pragma unroll
    for (int j = 0; j < 2; ++j) {
      const int u = j * 256 + wv * 64 + lane;
      const int r = u >> 2, c = (u & 3) * 8;
      const int gm = min(m0 + r, M - 1);
      gld16(A + (size_t)gm * K + k0 + c, As + (size_t)u * 8);
    }
#pragma unroll
    for (int j = 0; j < 2; ++j) {
      const int u = j * 256 + wv * 64 + lane;
      const int r = u >> 2, c = (u & 3) * 8;
      gld16(W + (size_t)(n0 + r) * K + k0 + c, Ws + (size_t)u * 8);
    }
    __syncthreads();
    short8 af[4], bfr[4];
#pragma unroll
    for (int i = 0; i < 4; ++i)
      af[i] = *(const short8*)(As + (wr * 64 + i * 16 + l15) * 32 + g * 8);
#pragma unroll
    for (int j = 0; j < 4; ++j)
      bfr[j] = *(const short8*)(Ws + (wc * 64 + j * 16 + l15) * 32 + g * 8);
    __builtin_amdgcn_s_setprio(1);
#pragma unroll
    for (int i = 0; i < 4; ++i)
#pragma unroll
      for (int j = 0; j < 4; ++j)
        acc[i][j] = __builtin_amdgcn_mfma_f32_16x16x32_bf16(af[i], bfr[j],
                                                            acc[i][j], 0, 0, 0);
    __builtin_amdgcn_s_setprio(0);
    __syncthreads();
  }
#pragma unroll
  for (int i = 0; i < 4; ++i) {
#pragma unroll
    for (int r = 0; r < 4; ++r) {
      const int row = m0 + wr * 64 + i * 16 + g * 4 + r;
      if (row >= M) continue;
#pragma unroll
      for (int j = 0; j < 4; ++j) {
        const int col = n0 + wc * 64 + j * 16 + l15;
        float v = acc[i][j][r];
        if (bias) v += bias[col];
        if (RELU) v = fmaxf(v, 0.f);
        if (BF16OUT)
          ((ushort*)Cv)[(size_t)row * N + col] = f2b(v);
        else
          ((float*)Cv)[(size_t)row * N + col] = v;
      }
    }
  }
}

// ---------------- conv as GEMM (K=3*FD over padded rows) -------------------
__global__ __launch_bounds__(256) void k_mmconv(const ushort* __restrict__ Ap,
                                                const ushort* __restrict__ W,
                                                const float* __restrict__ bias,
                                                float* __restrict__ Y) {
  constexpr int K = 3 * FD;
  __shared__ __align__(16) ushort As[128 * 32];
  __shared__ __align__(16) ushort Ws[128 * 32];
  const int tid = threadIdx.x;
  const int lane = tid & 63, wv = tid >> 6;
  const int l15 = lane & 15, g = lane >> 4;
  const int wr = wv >> 1, wc = wv & 1;
  int bx = blockIdx.x, by = blockIdx.y;
  const int nwg = gridDim.x * gridDim.y;
  if ((nwg & 7) == 0) {
    int bid = by * gridDim.x + bx;
    bid = (bid & 7) * (nwg >> 3) + (bid >> 3);
    bx = bid % gridDim.x;
    by = bid / gridDim.x;
  }
  const int m0 = by * 128, n0 = bx * 128;
  f32x4 acc[4][4];
#pragma unroll
  for (int i = 0; i < 4; ++i)
#pragma unroll
    for (int j = 0; j < 4; ++j) acc[i][j] = (f32x4){0.f, 0.f, 0.f, 0.f};

  for (int k0 = 0; k0 < K; k0 += 32) {
    const int tau = k0 >> 10;
    const int i0 = k0 & 1023;
#pragma unroll
    for (int j = 0; j < 2; ++j) {
      const int u = j * 256 + wv * 64 + lane;
      const int r = u >> 2, c = (u & 3) * 8;
      const int rm = m0 + r;
      const int b = rm >> 11, t = rm & 2047;
      gld16(Ap + ((size_t)(b * (TN + 2) + t + tau) * FD + i0 + c),
            As + (size_t)u * 8);
    }
#pragma unroll
    for (int j = 0; j < 2; ++j) {
      const int u = j * 256 + wv * 64 + lane;
      const int r = u >> 2, c = (u & 3) * 8;
      gld16(W + (size_t)(n0 + r) * K + k0 + c, Ws + (size_t)u * 8);
    }
    __syncthreads();
    short8 af[4], bfr[4];
#pragma unroll
    for (int i = 0; i < 4; ++i)
      af[i] = *(const short8*)(As + (wr * 64 + i * 16 + l15) * 32 + g * 8);
#pragma unroll
    for (int j = 0; j < 4; ++j)
      bfr[j] = *(const short8*)(Ws + (wc * 64 + j * 16 + l15) * 32 + g * 8);
    __builtin_amdgcn_s_setprio(1);
#pragma unroll
    for (int i = 0; i < 4; ++i)
#pragma unroll
      for (int j = 0; j < 4; ++j)
        acc[i][j] = __builtin_amdgcn_mfma_f32_16x16x32_bf16(af[i], bfr[j],
                                                            acc[i][j], 0, 0, 0);
    __builtin_amdgcn_s_setprio(0);
    __syncthreads();
  }
#pragma unroll
  for (int i = 0; i < 4; ++i) {
#pragma unroll
    for (int r = 0; r < 4; ++r) {
      const int rm = m0 + wr * 64 + i * 16 + g * 4 + r;
      const int b = rm >> 11, t = rm & 2047;
#pragma unroll
      for (int j = 0; j < 4; ++j) {
        const int col = n0 + wc * 64 + j * 16 + l15;
        const float v = fmaxf(acc[i][j][r] + bias[col], 0.f);
        Y[((size_t)(b * FD + col)) * TN + t] = v;
      }
    }
  }
}

// ---------------- flash attention (packed QKV input) -----------------------
__global__ __launch_bounds__(256) void k_fattn(const ushort* __restrict__ Qg,
                                               const ushort* __restrict__ Kg,
                                               const ushort* __restrict__ Vt,
                                               ushort* __restrict__ Og) {
  __shared__ __align__(16) ushort Ks[64 * 128];
  __shared__ __align__(16) ushort Vs[128 * 64];
  __shared__ __align__(16) ushort Ps[4][16 * 64];
  const int tid = threadIdx.x, lane = tid & 63, wv = tid >> 6;
  const int l15 = lane & 15, g = lane >> 4;
  const int b = blockIdx.z, h = blockIdx.y, q0 = blockIdx.x * 64;
  const size_t rowBase = (size_t)b * SN;
  const int hoff = h * DH;
  const size_t vbase = (size_t)(b * HN + h) * DH * SN;

  short8 qf[4];
  const int qrow = min(q0 + wv * 16 + l15, SN - 1);
#pragma unroll
  for (int c = 0; c < 4; ++c)
    qf[c] = *(const short8*)(Qg + (rowBase + qrow) * SF + hoff + c * 32 + g * 8);

  f32x4 o[8];
#pragma unroll
  for (int dt = 0; dt < 8; ++dt) o[dt] = (f32x4){0.f, 0.f, 0.f, 0.f};
  float m_run = -1.0e30f, l_run = 0.f;
  const char* KsB = (const char*)Ks;
  const char* VsB = (const char*)Vs;
  char* PsB = (char*)&Ps[wv][0];

  for (int kv0 = 0; kv0 < SN; kv0 += 64) {
    // stage K tile [64 rows][16 slots of 16B], slot s holds chunk s^(row&7)
#pragma unroll
    for (int j = 0; j < 4; ++j) {
      const int su = j * 256 + wv * 64 + lane;
      const int row = su >> 4, s = su & 15;
      const int c16 = s ^ (row & 7);
      const int krow = min(kv0 + row, SN - 1);
      gld16(Kg + (rowBase + krow) * SF + hoff + c16 * 8, Ks + (size_t)su * 8);
    }
    // stage Vt tile [128 rows][8 slots of 16B]
#pragma unroll
    for (int j = 0; j < 4; ++j) {
      const int su = j * 256 + wv * 64 + lane;
      const int row = su >> 3, s = su & 7;
      const int cc = s ^ (row & 7);
      const int kvc = min(kv0 + cc * 8, SN - 8);
      gld16(Vt + vbase + (size_t)row * SN + kvc, Vs + (size_t)su * 8);
    }
    __syncthreads();

    // S^T = K · Q^T
    f32x4 st[4];
    __builtin_amdgcn_s_setprio(1);
#pragma unroll
    for (int kt = 0; kt < 4; ++kt) {
      f32x4 s4 = (f32x4){0.f, 0.f, 0.f, 0.f};
      const int row = kt * 16 + l15;
#pragma unroll
      for (int c = 0; c < 4; ++c) {
        const short8 kf = *(const short8*)(
            KsB + row * 256 + (((c * 4 + g) ^ (row & 7)) << 4));
        s4 = __builtin_amdgcn_mfma_f32_16x16x32_bf16(kf, qf[c], s4, 0, 0, 0);
      }
      st[kt] = s4;
    }
    __builtin_amdgcn_s_setprio(0);

    // online softmax, raw-score units, base-2
    float praw[16];
    float pm = -1.0e30f;
#pragma unroll
    for (int kt = 0; kt < 4; ++kt)
#pragma unroll
      for (int r = 0; r < 4; ++r) {
        const int kvg = kv0 + kt * 16 + g * 4 + r;
        const float sc = (kvg < SN) ? st[kt][r] : -1.0e30f;
        praw[kt * 4 + r] = sc;
        pm = fmaxf(pm, sc);
      }
    pm = fmaxf(pm, __shfl_xor(pm, 16));
    pm = fmaxf(pm, __shfl_xor(pm, 32));
    if (!__all(pm <= m_run + 62.0f)) {  // defer-max (T13)
      const float m_new = fmaxf(m_run, pm);
      const float alpha = exp2_fast(C2 * (m_run - m_new));
      float ar[4];
#pragma unroll
      for (int r = 0; r < 4; ++r) ar[r] = __shfl(alpha, g * 4 + r);
#pragma unroll
      for (int dt = 0; dt < 8; ++dt)
#pragma unroll
        for (int r = 0; r < 4; ++r) o[dt][r] *= ar[r];
      l_run *= alpha;
      m_run = m_new;
    }
    const float nCm = -C2 * m_run;
    float pfl[16];
    float lsum = 0.f;
#pragma unroll
    for (int i = 0; i < 16; ++i) {
      pfl[i] = exp2_fast(fmaf(C2, praw[i], nCm));
      lsum += pfl[i];
    }
    lsum += __shfl_xor(lsum, 16);
    lsum += __shfl_xor(lsum, 32);
    l_run += lsum;

    // write P: row l15, 16B slots XOR-swizzled by (l15&7)
#pragma unroll
    for (int kt = 0; kt < 4; ++kt) {
      const uint lo = cvt_pk_bf16(pfl[kt * 4 + 0], pfl[kt * 4 + 1]);
      const uint hi = cvt_pk_bf16(pfl[kt * 4 + 2], pfl[kt * 4 + 3]);
      const int slot = (kt * 2 + (g >> 1)) ^ (l15 & 7);
      *(uint2*)(PsB + l15 * 128 + slot * 16 + (g & 1) * 8) = make_uint2(lo, hi);
    }

    // PV: O += P · V
    __builtin_amdgcn_s_setprio(1);
#pragma unroll
    for (int c2 = 0; c2 < 2; ++c2) {
      const int pslot = (c2 * 4 + g) ^ (l15 & 7);
      const short8 pf = *(const short8*)(PsB + l15 * 128 + pslot * 16);
#pragma unroll
      for (int dt = 0; dt < 8; ++dt) {
        const int row = dt * 16 + l15;
        const short8 vf = *(const short8*)(
            VsB + row * 128 + (((c2 * 4 + g) ^ (row & 7)) << 4));
        o[dt] = __builtin_amdgcn_mfma_f32_16x16x32_bf16(pf, vf, o[dt], 0, 0, 0);
      }
    }
    __builtin_amdgcn_s_setprio(0);
    __syncthreads();
  }

  const float invl = 1.f / l_run;
  float ir[4];
#pragma unroll
  for (int r = 0; r < 4; ++r) ir[r] = __shfl(invl, g * 4 + r);
#pragma unroll
  for (int r = 0; r < 4; ++r) {
    const int orow = q0 + wv * 16 + g * 4 + r;
    if (orow >= SN) continue;
#pragma unroll
    for (int dt = 0; dt < 8; ++dt)
      Og[(rowBase + orow) * FD + hoff + dt * 16 + l15] = f2b(o[dt][r] * ir[r]);
  }
}

// ---------------- fused residual + LayerNorm -------------------------------
__global__ __launch_bounds__(256) void k_add_ln(float* __restrict__ s,
                                                ushort* __restrict__ sb,
                                                const float* __restrict__ d,
                                                const float* __restrict__ g,
                                                const float* __restrict__ be) {
  __shared__ float red[4];
  const int row = blockIdx.x;
  const size_t off = (size_t)row * FD;
  const int tid = threadIdx.x;
  float v[4];
  float sum = 0.f;
#pragma unroll
  for (int i = 0; i < 4; ++i) {
    const int c = tid + 256 * i;
    v[i] = s[off + c] + d[off + c];
    sum += v[i];
  }
#pragma unroll
  for (int o = 32; o; o >>= 1) sum += __shfl_xor(sum, o);
  if ((tid & 63) == 0) red[tid >> 6] = sum;
  __syncthreads();
  sum = red[0] + red[1] + red[2] + red[3];
  const float mu = sum * (1.f / FD);
  float vs = 0.f;
#pragma unroll
  for (int i = 0; i < 4; ++i) {
    const float t = v[i] - mu;
    vs += t * t;
  }
  __syncthreads();
#pragma unroll
  for (int o = 32; o; o >>= 1) vs += __shfl_xor(vs, o);
  if ((tid & 63) == 0) red[tid >> 6] = vs;
  __syncthreads();
  vs = red[0] + red[1] + red[2] + red[3];
  const float rstd = rsqrtf(vs * (1.f / FD) + 1e-5f);
#pragma unroll
  for (int i = 0; i < 4; ++i) {
    const int c = tid + 256 * i;
    const float val = (v[i] - mu) * rstd * g[c] + be[c];
    s[off + c] = val;
    sb[off + c] = f2b(val);
  }
}

// ---------------------------------------------------------------------------
extern "C" void kernel_launch(void* const* d_in, const int* in_sizes, int n_in,
                              void* d_out, int out_size, void* d_ws,
                              size_t ws_size, hipStream_t stream) {
  const float* x      = (const float*)d_in[0];
  const float* proto  = (const float*)d_in[1];
  const float* wq     = (const float*)d_in[2];
  const float* bq     = (const float*)d_in[3];
  const float* wk     = (const float*)d_in[4];
  const float* bk     = (const float*)d_in[5];
  const float* in_w   = (const float*)d_in[6];
  const float* in_b   = (const float*)d_in[7];
  const float* out_w  = (const float*)d_in[8];
  const float* out_b  = (const float*)d_in[9];
  const float* l1_w   = (const float*)d_in[10];
  const float* l1_b   = (const float*)d_in[11];
  const float* l2_w   = (const float*)d_in[12];
  const float* l2_b   = (const float*)d_in[13];
  const float* ln1_g  = (const float*)d_in[14];
  const float* ln1_b  = (const float*)d_in[15];
  const float* ln2_g  = (const float*)d_in[16];
  const float* ln2_b  = (const float*)d_in[17];
  const float* emb_w  = (const float*)d_in[18];
  const float* emb_b  = (const float*)d_in[19];

  char* p = (char*)d_ws;
  auto take = [&](size_t bytes) {
    char* r = p;
    p += (bytes + 255) & ~(size_t)255;
    return r;
  };
  const size_t MF = (size_t)MR * FD;
  const size_t FF = (size_t)FD * FD;
  float*  src   = (float*)take(MF * 4);
  ushort* srcb  = (ushort*)take(MF * 2);
  ushort* bQKV  = (ushort*)take((size_t)MR * SF * 2);   // 55 MB, multi-aliased
  ushort* bVt   = (ushort*)take((size_t)BN * HN * DH * SN * 2);
  ushort* bO    = (ushort*)take(MF * 2);
  ushort* bFF   = (ushort*)take((size_t)MR * DF * 2);
  ushort* wQKV  = (ushort*)take((size_t)2 * 3 * FF * 2);  // packed weights
  ushort* wOut  = (ushort*)take((size_t)2 * FF * 2);
  ushort* wL1   = (ushort*)take((size_t)2 * DF * FD * 2);
  ushort* wL2   = (ushort*)take((size_t)2 * FD * DF * 2);
  float*  bqkv  = (float*)take((size_t)2 * SF * 4);
  // aliases inside bQKV (lifetimes disjoint from activation use):
  ushort* wT     = bQKV;                       // prep: 4 * F*F bf16
  ushort* wInQK  = bQKV + 4 * FF;              // prep: 4 * F*F bf16
  float*  aOut   = (float*)bQKV;               // post-attn / post-FFN2 fp32
  ushort* srcPad = bQKV;                       // tail: B*(TN+2)*F bf16
  ushort* convW  = bQKV + (size_t)10 * 1024 * 1024;  // tail: 3*F*F bf16

  // ---- prep (all weight-only work hoisted) ----
  k_build<<<MR, 256, 0, stream>>>(x, proto, src, srcb);
  k_cvt<<<1024, 256, 0, stream>>>(in_w, wInQK, 2 * FF);
  k_cvt<<<1024, 256, 0, stream>>>(in_w + 3 * FF, wInQK + 2 * FF, 2 * FF);
  k_cvt<<<1024, 256, 0, stream>>>(in_w + 2 * FF, wQKV + 2 * FF, FF);
  k_cvt<<<1024, 256, 0, stream>>>(in_w + 5 * FF, wQKV + 5 * FF, FF);
  k_cvt<<<1024, 256, 0, stream>>>(out_w, wOut, 2 * FF);
  k_cvt<<<256, 256, 0, stream>>>(l1_w, wL1, 2 * DF * FD);
  k_cvt<<<256, 256, 0, stream>>>(l2_w, wL2, 2 * FD * DF);
  k_cvtT<<<dim3(32, 32, 2), 256, 0, stream>>>(wq, wT);
  k_cvtT<<<dim3(32, 32, 2), 256, 0, stream>>>(wk, wT + 2 * FF);
  for (int l = 0; l < 2; ++l)
    for (int qk = 0; qk < 2; ++qk)
      k_mm<false, true><<<dim3(8, 8), 256, 0, stream>>>(
          wInQK + (size_t)(l * 2 + qk) * FF, wT + (size_t)(qk * 2 + l) * FF,
          nullptr, wQKV + (size_t)(l * 3 + qk) * FF, FD, FD, FD);
  k_beff<<<dim3(FD, 2), 256, 0, stream>>>(in_w, bq, in_b, bqkv, 0);
  k_beff<<<dim3(FD, 2), 256, 0, stream>>>(in_w, bk, in_b, bqkv, 1);
  k_copyv<<<dim3(4, 2), 256, 0, stream>>>(in_b, bqkv);

  // ---- layers ----
  for (int l = 0; l < 2; ++l) {
    k_mm<false, true><<<dim3(SF / 128, (MR + 127) / 128), 256, 0, stream>>>(
        srcb, wQKV + (size_t)l * 3 * FF, bqkv + (size_t)l * SF, bQKV, MR, SF,
        FD);
    k_vT<<<dim3((SN + 31) / 32, DH / 32, BN * HN), 256, 0, stream>>>(
        bQKV + 2 * FD, bVt);
    k_fattn<<<dim3((SN + 63) / 64, HN, BN), 256, 0, stream>>>(
        bQKV, bQKV + FD, bVt, bO);
    k_mm<false, false><<<dim3(FD / 128, (MR + 127) / 128), 256, 0, stream>>>(
        bO, wOut + (size_t)l * FF, out_b + (size_t)l * FD, aOut, MR, FD, FD);
    k_add_ln<<<MR, 256, 0, stream>>>(src, srcb, aOut, ln1_g + (size_t)l * FD,
                                     ln1_b + (size_t)l * FD);
    k_mm<true, true><<<dim3(DF / 128, (MR + 127) / 128), 256, 0, stream>>>(
        srcb, wL1 + (size_t)l * DF * FD, l1_b + (size_t)l * DF, bFF, MR, DF,
        FD);
    k_mm<false, false><<<dim3(FD / 128, (MR + 127) / 128), 256, 0, stream>>>(
        bFF, wL2 + (size_t)l * FD * DF, l2_b + (size_t)l * FD, aOut, MR, FD,
        DF);
    k_add_ln<<<MR, 256, 0, stream>>>(src, srcb, aOut, ln2_g + (size_t)l * FD,
                                     ln2_b + (size_t)l * FD);
  }

  // ---- conv head ----
  k_convw<<<1024, 256, 0, stream>>>(emb_w, convW);
  k_pad<<<dim3(TN + 2, BN), 256, 0, stream>>>(srcb, srcPad);
  k_mmconv<<<dim3(FD / 128, (BN * TN) / 128), 256, 0, stream>>>(
      srcPad, convW, emb_b, (float*)d_out);
}

// Round 4
// 1062.143 us; speedup vs baseline: 14.5514x; 1.0250x over previous
//
#include <hip/hip_runtime.h>
#include <hip/hip_bf16.h>

// ---------------------------------------------------------------------------
// Round 4: attention VALU diet part 2 (MFMA row-sum via ones-fragment,
// tail-specialized masking, v_max3 tree, shuffle-free epilogue) + bf16
// residual path (bf16 GEMM outputs feeding vectorized add+LN).
// ---------------------------------------------------------------------------

constexpr int BN = 4, TN = 2048, FD = 1024, CP = 200, SN = TN + CP;  // 2248
constexpr int HN = 8, DH = 128, DF = 128, MR = BN * SN;              // 8992
constexpr int SF = 3 * FD;                                           // 3072
constexpr float C2 = 0.12751744f;  // (1/sqrt(128)) * log2(e)

typedef __attribute__((ext_vector_type(8))) short short8;
typedef __attribute__((ext_vector_type(4))) float f32x4;

__device__ __forceinline__ ushort f2b(float f) {
  union { float f; uint u; } v{f};
  return (ushort)((v.u + 0x7fffu + ((v.u >> 16) & 1u)) >> 16);
}
__device__ __forceinline__ float b2f(ushort u) {
  union { uint u; float f; } v{(uint)u << 16};
  return v.f;
}
__device__ __forceinline__ uint cvt_pk_bf16(float a, float b) {
  uint r;
  asm("v_cvt_pk_bf16_f32 %0, %1, %2" : "=v"(r) : "v"(a), "v"(b));
  return r;
}
__device__ __forceinline__ float exp2_fast(float x) {
  float r;
  asm("v_exp_f32 %0, %1" : "=v"(r) : "v"(x));
  return r;
}
__device__ __forceinline__ float max3f(float a, float b, float c) {
  float r;
  asm("v_max3_f32 %0, %1, %2, %3" : "=v"(r) : "v"(a), "v"(b), "v"(c));
  return r;
}
__device__ __forceinline__ void gld16(const void* g, void* l) {
  __builtin_amdgcn_global_load_lds(
      (const __attribute__((address_space(1))) void*)g,
      (__attribute__((address_space(3))) void*)l, 16, 0, 0);
}

// ---------------- build src fp32 + bf16 mirror (row/block) -----------------
__global__ __launch_bounds__(256) void k_build(const float* __restrict__ x,
                                               const float* __restrict__ proto,
                                               float* __restrict__ src,
                                               ushort* __restrict__ srcb) {
  const int row = blockIdx.x;  // 0..MR-1
  const int b = row / SN, s = row % SN;
  const int f = threadIdx.x * 4;
  const size_t o = (size_t)row * FD + f;
  float4 v;
  if (s < TN) {
    v = *(const float4*)(x + ((size_t)b * TN + s) * FD + f);
  } else {
    const int c = s - TN;
    v.x = proto[(size_t)(f + 0) * CP + c];
    v.y = proto[(size_t)(f + 1) * CP + c];
    v.z = proto[(size_t)(f + 2) * CP + c];
    v.w = proto[(size_t)(f + 3) * CP + c];
  }
  *(float4*)(src + o) = v;
  ushort4 u{f2b(v.x), f2b(v.y), f2b(v.z), f2b(v.w)};
  *(ushort4*)(srcb + o) = u;
}

// ---------------- flat fp32 -> bf16 (vec4) ---------------------------------
__global__ __launch_bounds__(256) void k_cvt(const float* __restrict__ in,
                                             ushort* __restrict__ out, int n) {
  const int n4 = n >> 2;
  for (int i = blockIdx.x * 256 + threadIdx.x; i < n4; i += gridDim.x * 256) {
    const float4 v = *(const float4*)(in + (size_t)i * 4);
    ushort4 u{f2b(v.x), f2b(v.y), f2b(v.z), f2b(v.w)};
    *(ushort4*)(out + (size_t)i * 4) = u;
  }
}

// ---------------- transpose-convert FxF fp32 -> bf16, z = layer ------------
__global__ __launch_bounds__(256) void k_cvtT(const float* __restrict__ Wg,
                                              ushort* __restrict__ WTg) {
  const float* W = Wg + (size_t)blockIdx.z * FD * FD;
  ushort* WT = WTg + (size_t)blockIdx.z * FD * FD;
  __shared__ float t[32][33];
  const int tx = threadIdx.x & 31, ty = threadIdx.x >> 5;
  const int x0 = blockIdx.x * 32, y0 = blockIdx.y * 32;
#pragma unroll
  for (int dy = 0; dy < 4; ++dy)
    t[ty + dy * 8][tx] = W[(size_t)(y0 + ty + dy * 8) * FD + x0 + tx];
  __syncthreads();
#pragma unroll
  for (int dy = 0; dy < 4; ++dy)
    WT[(size_t)(x0 + ty + dy * 8) * FD + y0 + tx] = f2b(t[tx][ty + dy * 8]);
}

// ---------------- per-(b,h) transpose V (from packed QKV) ------------------
__global__ __launch_bounds__(256) void k_vT(const ushort* __restrict__ V,
                                            ushort* __restrict__ Vt) {
  __shared__ ushort t[32][34];
  const int tx = threadIdx.x & 31, ty = threadIdx.x >> 5;
  const int s0 = blockIdx.x * 32, d0 = blockIdx.y * 32, bh = blockIdx.z;
  const int b = bh >> 3, h = bh & 7;
#pragma unroll
  for (int dy = 0; dy < 4; ++dy) {
    const int s = min(s0 + ty + dy * 8, SN - 1);
    t[ty + dy * 8][tx] = V[((size_t)b * SN + s) * SF + h * DH + d0 + tx];
  }
  __syncthreads();
#pragma unroll
  for (int dy = 0; dy < 4; ++dy) {
    const int s = s0 + tx;
    if (s < SN)
      Vt[((size_t)bh * DH + d0 + ty + dy * 8) * SN + s] = t[tx][ty + dy * 8];
  }
}

// ---------------- conv weight repack: cw[o][tau*F+i] = W[o][i][tau] --------
__global__ __launch_bounds__(256) void k_convw(const float* __restrict__ W,
                                               ushort* __restrict__ out) {
  const int n = FD * FD * 3;
  for (int idx = blockIdx.x * 256 + threadIdx.x; idx < n;
       idx += gridDim.x * 256) {
    const int o = idx / (FD * 3);
    const int rem = idx % (FD * 3);
    const int tau = rem >> 10, i = rem & 1023;
    out[idx] = f2b(W[(size_t)o * (FD * 3) + i * 3 + tau]);
  }
}

// ---------------- zero-padded bf16 src for conv (row/block) ----------------
__global__ __launch_bounds__(256) void k_pad(const ushort* __restrict__ sb,
                                             ushort* __restrict__ pad) {
  const int r = blockIdx.x, b = blockIdx.y;  // r in [0, TN+2)
  const int f = threadIdx.x * 4;
  ushort4 v{0, 0, 0, 0};
  if (r >= 1 && r <= TN)
    v = *(const ushort4*)(sb + ((size_t)b * SN + (r - 1)) * FD + f);
  *(ushort4*)(pad + ((size_t)b * (TN + 2) + r) * FD + f) = v;
}

// ---------------- effective bias -------------------------------------------
__global__ __launch_bounds__(256) void k_beff(const float* __restrict__ in_w,
                                              const float* __restrict__ bvec,
                                              const float* __restrict__ in_b,
                                              float* __restrict__ out, int qk) {
  const int n = blockIdx.x, l = blockIdx.y, tid = threadIdx.x;
  const float* Win = in_w + (size_t)(l * 3 + qk) * FD * FD;
  const float* bv = bvec + (size_t)l * FD;
  float s = 0.f;
  for (int j = tid; j < FD; j += 256) s += Win[(size_t)n * FD + j] * bv[j];
  __shared__ float red[4];
#pragma unroll
  for (int o = 32; o; o >>= 1) s += __shfl_xor(s, o);
  if ((tid & 63) == 0) red[tid >> 6] = s;
  __syncthreads();
  if (tid == 0)
    out[l * 3 * FD + qk * FD + n] =
        red[0] + red[1] + red[2] + red[3] + in_b[l * 3 * FD + qk * FD + n];
}

// ---------------- copy V bias rows -----------------------------------------
__global__ __launch_bounds__(256) void k_copyv(const float* __restrict__ in_b,
                                               float* __restrict__ bqkv) {
  const int l = blockIdx.y;
  const int i = blockIdx.x * 256 + threadIdx.x;
  bqkv[l * 3 * FD + 2 * FD + i] = in_b[l * 3 * FD + 2 * FD + i];
}

// ---------------- bf16 MFMA GEMM (m97 structure + XCD swizzle) -------------
template <bool RELU, bool BF16OUT>
__global__ __launch_bounds__(256) void k_mm(const ushort* __restrict__ A,
                                            const ushort* __restrict__ W,
                                            const float* __restrict__ bias,
                                            void* __restrict__ Cv,
                                            int M, int N, int K) {
  __shared__ __align__(16) ushort As[128 * 32];
  __shared__ __align__(16) ushort Ws[128 * 32];
  const int tid = threadIdx.x;
  const int lane = tid & 63, wv = tid >> 6;
  const int l15 = lane & 15, g = lane >> 4;
  const int wr = wv >> 1, wc = wv & 1;
  int bx = blockIdx.x, by = blockIdx.y;
  const int nwg = gridDim.x * gridDim.y;
  if ((nwg & 7) == 0) {  // bijective XCD swizzle (T1)
    int bid = by * gridDim.x + bx;
    bid = (bid & 7) * (nwg >> 3) + (bid >> 3);
    bx = bid % gridDim.x;
    by = bid / gridDim.x;
  }
  const int m0 = by * 128, n0 = bx * 128;
  f32x4 acc[4][4];
#pragma unroll
  for (int i = 0; i < 4; ++i)
#pragma unroll
    for (int j = 0; j < 4; ++j) acc[i][j] = (f32x4){0.f, 0.f, 0.f, 0.f};

  for (int k0 = 0; k0 < K; k0 += 32) {
#pragma unroll
    for (int j = 0; j < 2; ++j) {
      const int u = j * 256 + wv * 64 + lane;
      const int r = u >> 2, c = (u & 3) * 8;
      const int gm = min(m0 + r, M - 1);
      gld16(A + (size_t)gm * K + k0 + c, As + (size_t)u * 8);
    }
#pragma unroll
    for (int j = 0; j < 2; ++j) {
      const int u = j * 256 + wv * 64 + lane;
      const int r = u >> 2, c = (u & 3) * 8;
      gld16(W + (size_t)(n0 + r) * K + k0 + c, Ws + (size_t)u * 8);
    }
    __syncthreads();
    short8 af[4], bfr[4];
#pragma unroll
    for (int i = 0; i < 4; ++i)
      af[i] = *(const short8*)(As + (wr * 64 + i * 16 + l15) * 32 + g * 8);
#pragma unroll
    for (int j = 0; j < 4; ++j)
      bfr[j] = *(const short8*)(Ws + (wc * 64 + j * 16 + l15) * 32 + g * 8);
    __builtin_amdgcn_s_setprio(1);
#pragma unroll
    for (int i = 0; i < 4; ++i)
#pragma unroll
      for (int j = 0; j < 4; ++j)
        acc[i][j] = __builtin_amdgcn_mfma_f32_16x16x32_bf16(af[i], bfr[j],
                                                            acc[i][j], 0, 0, 0);
    __builtin_amdgcn_s_setprio(0);
    __syncthreads();
  }
#pragma unroll
  for (int i = 0; i < 4; ++i) {
#pragma unroll
    for (int r = 0; r < 4; ++r) {
      const int row = m0 + wr * 64 + i * 16 + g * 4 + r;
      if (row >= M) continue;
#pragma unroll
      for (int j = 0; j < 4; ++j) {
        const int col = n0 + wc * 64 + j * 16 + l15;
        float v = acc[i][j][r];
        if (bias) v += bias[col];
        if (RELU) v = fmaxf(v, 0.f);
        if (BF16OUT)
          ((ushort*)Cv)[(size_t)row * N + col] = f2b(v);
        else
          ((float*)Cv)[(size_t)row * N + col] = v;
      }
    }
  }
}

// ---------------- conv as GEMM (K=3*FD over padded rows) -------------------
__global__ __launch_bounds__(256) void k_mmconv(const ushort* __restrict__ Ap,
                                                const ushort* __restrict__ W,
                                                const float* __restrict__ bias,
                                                float* __restrict__ Y) {
  constexpr int K = 3 * FD;
  __shared__ __align__(16) ushort As[128 * 32];
  __shared__ __align__(16) ushort Ws[128 * 32];
  const int tid = threadIdx.x;
  const int lane = tid & 63, wv = tid >> 6;
  const int l15 = lane & 15, g = lane >> 4;
  const int wr = wv >> 1, wc = wv & 1;
  int bx = blockIdx.x, by = blockIdx.y;
  const int nwg = gridDim.x * gridDim.y;
  if ((nwg & 7) == 0) {
    int bid = by * gridDim.x + bx;
    bid = (bid & 7) * (nwg >> 3) + (bid >> 3);
    bx = bid % gridDim.x;
    by = bid / gridDim.x;
  }
  const int m0 = by * 128, n0 = bx * 128;
  f32x4 acc[4][4];
#pragma unroll
  for (int i = 0; i < 4; ++i)
#pragma unroll
    for (int j = 0; j < 4; ++j) acc[i][j] = (f32x4){0.f, 0.f, 0.f, 0.f};

  for (int k0 = 0; k0 < K; k0 += 32) {
    const int tau = k0 >> 10;
    const int i0 = k0 & 1023;
#pragma unroll
    for (int j = 0; j < 2; ++j) {
      const int u = j * 256 + wv * 64 + lane;
      const int r = u >> 2, c = (u & 3) * 8;
      const int rm = m0 + r;
      const int b = rm >> 11, t = rm & 2047;
      gld16(Ap + ((size_t)(b * (TN + 2) + t + tau) * FD + i0 + c),
            As + (size_t)u * 8);
    }
#pragma unroll
    for (int j = 0; j < 2; ++j) {
      const int u = j * 256 + wv * 64 + lane;
      const int r = u >> 2, c = (u & 3) * 8;
      gld16(W + (size_t)(n0 + r) * K + k0 + c, Ws + (size_t)u * 8);
    }
    __syncthreads();
    short8 af[4], bfr[4];
#pragma unroll
    for (int i = 0; i < 4; ++i)
      af[i] = *(const short8*)(As + (wr * 64 + i * 16 + l15) * 32 + g * 8);
#pragma unroll
    for (int j = 0; j < 4; ++j)
      bfr[j] = *(const short8*)(Ws + (wc * 64 + j * 16 + l15) * 32 + g * 8);
    __builtin_amdgcn_s_setprio(1);
#pragma unroll
    for (int i = 0; i < 4; ++i)
#pragma unroll
      for (int j = 0; j < 4; ++j)
        acc[i][j] = __builtin_amdgcn_mfma_f32_16x16x32_bf16(af[i], bfr[j],
                                                            acc[i][j], 0, 0, 0);
    __builtin_amdgcn_s_setprio(0);
    __syncthreads();
  }
#pragma unroll
  for (int i = 0; i < 4; ++i) {
#pragma unroll
    for (int r = 0; r < 4; ++r) {
      const int rm = m0 + wr * 64 + i * 16 + g * 4 + r;
      const int b = rm >> 11, t = rm & 2047;
#pragma unroll
      for (int j = 0; j < 4; ++j) {
        const int col = n0 + wc * 64 + j * 16 + l15;
        const float v = fmaxf(acc[i][j][r] + bias[col], 0.f);
        Y[((size_t)(b * FD + col)) * TN + t] = v;
      }
    }
  }
}

// ---------------- flash attention (packed QKV input) -----------------------
__global__ __launch_bounds__(256) void k_fattn(const ushort* __restrict__ Qg,
                                               const ushort* __restrict__ Kg,
                                               const ushort* __restrict__ Vt,
                                               ushort* __restrict__ Og) {
  __shared__ __align__(16) ushort Ks[64 * 128];
  __shared__ __align__(16) ushort Vs[128 * 64];
  __shared__ __align__(16) ushort Ps[4][16 * 64];
  const int tid = threadIdx.x, lane = tid & 63, wv = tid >> 6;
  const int l15 = lane & 15, g = lane >> 4;
  const int b = blockIdx.z, h = blockIdx.y, q0 = blockIdx.x * 64;
  const size_t rowBase = (size_t)b * SN;
  const int hoff = h * DH;
  const size_t vbase = (size_t)(b * HN + h) * DH * SN;

  short8 qf[4];
  const int qrow = min(q0 + wv * 16 + l15, SN - 1);
#pragma unroll
  for (int c = 0; c < 4; ++c)
    qf[c] = *(const short8*)(Qg + (rowBase + qrow) * SF + hoff + c * 32 + g * 8);

  short8 onesf;
#pragma unroll
  for (int i = 0; i < 8; ++i) onesf[i] = (short)0x3F80;  // bf16 1.0

  f32x4 o[8];
#pragma unroll
  for (int dt = 0; dt < 8; ++dt) o[dt] = (f32x4){0.f, 0.f, 0.f, 0.f};
  f32x4 lacc = (f32x4){0.f, 0.f, 0.f, 0.f};  // MFMA row-sum of P
  float m_run = -1.0e30f;
  const char* KsB = (const char*)Ks;
  const char* VsB = (const char*)Vs;
  char* PsB = (char*)&Ps[wv][0];

  for (int kv0 = 0; kv0 < SN; kv0 += 64) {
    // stage K tile [64 rows][16 slots of 16B], slot s holds chunk s^(row&7)
#pragma unroll
    for (int j = 0; j < 4; ++j) {
      const int su = j * 256 + wv * 64 + lane;
      const int row = su >> 4, s = su & 15;
      const int c16 = s ^ (row & 7);
      const int krow = min(kv0 + row, SN - 1);
      gld16(Kg + (rowBase + krow) * SF + hoff + c16 * 8, Ks + (size_t)su * 8);
    }
    // stage Vt tile [128 rows][8 slots of 16B]
#pragma unroll
    for (int j = 0; j < 4; ++j) {
      const int su = j * 256 + wv * 64 + lane;
      const int row = su >> 3, s = su & 7;
      const int cc = s ^ (row & 7);
      const int kvc = min(kv0 + cc * 8, SN - 8);
      gld16(Vt + vbase + (size_t)row * SN + kvc, Vs + (size_t)su * 8);
    }
    __syncthreads();

    // S^T = K · Q^T
    f32x4 st[4];
    __builtin_amdgcn_s_setprio(1);
#pragma unroll
    for (int kt = 0; kt < 4; ++kt) {
      f32x4 s4 = (f32x4){0.f, 0.f, 0.f, 0.f};
      const int row = kt * 16 + l15;
#pragma unroll
      for (int c = 0; c < 4; ++c) {
        const short8 kf = *(const short8*)(
            KsB + row * 256 + (((c * 4 + g) ^ (row & 7)) << 4));
        s4 = __builtin_amdgcn_mfma_f32_16x16x32_bf16(kf, qf[c], s4, 0, 0, 0);
      }
      st[kt] = s4;
    }
    __builtin_amdgcn_s_setprio(0);

    // online softmax, raw-score units, base-2
    float praw[16];
#pragma unroll
    for (int kt = 0; kt < 4; ++kt)
#pragma unroll
      for (int r = 0; r < 4; ++r) praw[kt * 4 + r] = st[kt][r];
    if (kv0 + 64 > SN) {  // only the last kv-tile has invalid columns
#pragma unroll
      for (int kt = 0; kt < 4; ++kt)
#pragma unroll
        for (int r = 0; r < 4; ++r)
          if (kv0 + kt * 16 + g * 4 + r >= SN) praw[kt * 4 + r] = -1.0e30f;
    }
    float pm = fmaxf(praw[0], praw[1]);
#pragma unroll
    for (int i = 2; i < 16; i += 2) pm = max3f(praw[i], praw[i + 1], pm);
    pm = fmaxf(pm, __shfl_xor(pm, 16));
    pm = fmaxf(pm, __shfl_xor(pm, 32));
    if (!__all(pm <= m_run + 62.0f)) {  // defer-max (T13)
      const float m_new = fmaxf(m_run, pm);
      const float alpha = exp2_fast(C2 * (m_run - m_new));
      float ar[4];
#pragma unroll
      for (int r = 0; r < 4; ++r) ar[r] = __shfl(alpha, g * 4 + r);
#pragma unroll
      for (int dt = 0; dt < 8; ++dt)
#pragma unroll
        for (int r = 0; r < 4; ++r) o[dt][r] *= ar[r];
#pragma unroll
      for (int r = 0; r < 4; ++r) lacc[r] *= ar[r];
      m_run = m_new;
    }
    const float nCm = -C2 * m_run;
    float pfl[16];
#pragma unroll
    for (int i = 0; i < 16; ++i) pfl[i] = exp2_fast(fmaf(C2, praw[i], nCm));

    // write P: row l15, 16B slots XOR-swizzled by (l15&7)
#pragma unroll
    for (int kt = 0; kt < 4; ++kt) {
      const uint lo = cvt_pk_bf16(pfl[kt * 4 + 0], pfl[kt * 4 + 1]);
      const uint hi = cvt_pk_bf16(pfl[kt * 4 + 2], pfl[kt * 4 + 3]);
      const int slot = (kt * 2 + (g >> 1)) ^ (l15 & 7);
      *(uint2*)(PsB + l15 * 128 + slot * 16 + (g & 1) * 8) = make_uint2(lo, hi);
    }

    // PV: O += P · V ; lacc += P · 1 (row-sum via matrix pipe)
    __builtin_amdgcn_s_setprio(1);
#pragma unroll
    for (int c2 = 0; c2 < 2; ++c2) {
      const int pslot = (c2 * 4 + g) ^ (l15 & 7);
      const short8 pf = *(const short8*)(PsB + l15 * 128 + pslot * 16);
      lacc = __builtin_amdgcn_mfma_f32_16x16x32_bf16(pf, onesf, lacc, 0, 0, 0);
#pragma unroll
      for (int dt = 0; dt < 8; ++dt) {
        const int row = dt * 16 + l15;
        const short8 vf = *(const short8*)(
            VsB + row * 128 + (((c2 * 4 + g) ^ (row & 7)) << 4));
        o[dt] = __builtin_amdgcn_mfma_f32_16x16x32_bf16(pf, vf, o[dt], 0, 0, 0);
      }
    }
    __builtin_amdgcn_s_setprio(0);
    __syncthreads();
  }

  float ir[4];
#pragma unroll
  for (int r = 0; r < 4; ++r) ir[r] = 1.f / lacc[r];
#pragma unroll
  for (int r = 0; r < 4; ++r) {
    const int orow = q0 + wv * 16 + g * 4 + r;
    if (orow >= SN) continue;
#pragma unroll
    for (int dt = 0; dt < 8; ++dt)
      Og[(rowBase + orow) * FD + hoff + dt * 16 + l15] = f2b(o[dt][r] * ir[r]);
  }
}

// ---------------- fused residual(bf16 delta) + LayerNorm, vec4 -------------
__global__ __launch_bounds__(256) void k_add_ln(float* __restrict__ s,
                                                ushort* __restrict__ sb,
                                                const ushort* __restrict__ d,
                                                const float* __restrict__ g,
                                                const float* __restrict__ be) {
  __shared__ float red[4];
  const int row = blockIdx.x;
  const int tid = threadIdx.x;
  const int c = tid * 4;
  const size_t off = (size_t)row * FD + c;
  const float4 sv = *(const float4*)(s + off);
  const ushort4 dv = *(const ushort4*)(d + off);
  float v[4] = {sv.x + b2f(dv.x), sv.y + b2f(dv.y), sv.z + b2f(dv.z),
                sv.w + b2f(dv.w)};
  float sum = v[0] + v[1] + v[2] + v[3];
#pragma unroll
  for (int o = 32; o; o >>= 1) sum += __shfl_xor(sum, o);
  if ((tid & 63) == 0) red[tid >> 6] = sum;
  __syncthreads();
  sum = red[0] + red[1] + red[2] + red[3];
  const float mu = sum * (1.f / FD);
  float vs = 0.f;
#pragma unroll
  for (int i = 0; i < 4; ++i) {
    const float t = v[i] - mu;
    vs += t * t;
  }
  __syncthreads();
#pragma unroll
  for (int o = 32; o; o >>= 1) vs += __shfl_xor(vs, o);
  if ((tid & 63) == 0) red[tid >> 6] = vs;
  __syncthreads();
  vs = red[0] + red[1] + red[2] + red[3];
  const float rstd = rsqrtf(vs * (1.f / FD) + 1e-5f);
  const float4 gv = *(const float4*)(g + c);
  const float4 bv = *(const float4*)(be + c);
  float out[4] = {(v[0] - mu) * rstd * gv.x + bv.x,
                  (v[1] - mu) * rstd * gv.y + bv.y,
                  (v[2] - mu) * rstd * gv.z + bv.z,
                  (v[3] - mu) * rstd * gv.w + bv.w};
  *(float4*)(s + off) = float4{out[0], out[1], out[2], out[3]};
  ushort4 u{f2b(out[0]), f2b(out[1]), f2b(out[2]), f2b(out[3])};
  *(ushort4*)(sb + off) = u;
}

// ---------------------------------------------------------------------------
extern "C" void kernel_launch(void* const* d_in, const int* in_sizes, int n_in,
                              void* d_out, int out_size, void* d_ws,
                              size_t ws_size, hipStream_t stream) {
  const float* x      = (const float*)d_in[0];
  const float* proto  = (const float*)d_in[1];
  const float* wq     = (const float*)d_in[2];
  const float* bq     = (const float*)d_in[3];
  const float* wk     = (const float*)d_in[4];
  const float* bk     = (const float*)d_in[5];
  const float* in_w   = (const float*)d_in[6];
  const float* in_b   = (const float*)d_in[7];
  const float* out_w  = (const float*)d_in[8];
  const float* out_b  = (const float*)d_in[9];
  const float* l1_w   = (const float*)d_in[10];
  const float* l1_b   = (const float*)d_in[11];
  const float* l2_w   = (const float*)d_in[12];
  const float* l2_b   = (const float*)d_in[13];
  const float* ln1_g  = (const float*)d_in[14];
  const float* ln1_b  = (const float*)d_in[15];
  const float* ln2_g  = (const float*)d_in[16];
  const float* ln2_b  = (const float*)d_in[17];
  const float* emb_w  = (const float*)d_in[18];
  const float* emb_b  = (const float*)d_in[19];

  char* p = (char*)d_ws;
  auto take = [&](size_t bytes) {
    char* r = p;
    p += (bytes + 255) & ~(size_t)255;
    return r;
  };
  const size_t MF = (size_t)MR * FD;
  const size_t FF = (size_t)FD * FD;
  float*  src   = (float*)take(MF * 4);
  ushort* srcb  = (ushort*)take(MF * 2);
  ushort* bQKV  = (ushort*)take((size_t)MR * SF * 2);   // 55 MB, multi-aliased
  ushort* bVt   = (ushort*)take((size_t)BN * HN * DH * SN * 2);
  ushort* bO    = (ushort*)take(MF * 2);
  ushort* bFF   = (ushort*)take((size_t)MR * DF * 2);
  ushort* wQKV  = (ushort*)take((size_t)2 * 3 * FF * 2);  // packed weights
  ushort* wOut  = (ushort*)take((size_t)2 * FF * 2);
  ushort* wL1   = (ushort*)take((size_t)2 * DF * FD * 2);
  ushort* wL2   = (ushort*)take((size_t)2 * FD * DF * 2);
  float*  bqkv  = (float*)take((size_t)2 * SF * 4);
  // aliases inside bQKV (lifetimes disjoint from activation use):
  ushort* wT     = bQKV;                       // prep: 4 * F*F bf16
  ushort* wInQK  = bQKV + 4 * FF;              // prep: 4 * F*F bf16
  ushort* bOut   = bQKV;                       // post-attn / post-FFN2 bf16
  ushort* srcPad = bQKV;                       // tail: B*(TN+2)*F bf16
  ushort* convW  = bQKV + (size_t)10 * 1024 * 1024;  // tail: 3*F*F bf16

  // ---- prep (all weight-only work hoisted) ----
  k_build<<<MR, 256, 0, stream>>>(x, proto, src, srcb);
  k_cvt<<<1024, 256, 0, stream>>>(in_w, wInQK, 2 * FF);
  k_cvt<<<1024, 256, 0, stream>>>(in_w + 3 * FF, wInQK + 2 * FF, 2 * FF);
  k_cvt<<<1024, 256, 0, stream>>>(in_w + 2 * FF, wQKV + 2 * FF, FF);
  k_cvt<<<1024, 256, 0, stream>>>(in_w + 5 * FF, wQKV + 5 * FF, FF);
  k_cvt<<<1024, 256, 0, stream>>>(out_w, wOut, 2 * FF);
  k_cvt<<<256, 256, 0, stream>>>(l1_w, wL1, 2 * DF * FD);
  k_cvt<<<256, 256, 0, stream>>>(l2_w, wL2, 2 * FD * DF);
  k_cvtT<<<dim3(32, 32, 2), 256, 0, stream>>>(wq, wT);
  k_cvtT<<<dim3(32, 32, 2), 256, 0, stream>>>(wk, wT + 2 * FF);
  for (int l = 0; l < 2; ++l)
    for (int qk = 0; qk < 2; ++qk)
      k_mm<false, true><<<dim3(8, 8), 256, 0, stream>>>(
          wInQK + (size_t)(l * 2 + qk) * FF, wT + (size_t)(qk * 2 + l) * FF,
          nullptr, wQKV + (size_t)(l * 3 + qk) * FF, FD, FD, FD);
  k_beff<<<dim3(FD, 2), 256, 0, stream>>>(in_w, bq, in_b, bqkv, 0);
  k_beff<<<dim3(FD, 2), 256, 0, stream>>>(in_w, bk, in_b, bqkv, 1);
  k_copyv<<<dim3(4, 2), 256, 0, stream>>>(in_b, bqkv);

  // ---- layers ----
  for (int l = 0; l < 2; ++l) {
    k_mm<false, true><<<dim3(SF / 128, (MR + 127) / 128), 256, 0, stream>>>(
        srcb, wQKV + (size_t)l * 3 * FF, bqkv + (size_t)l * SF, bQKV, MR, SF,
        FD);
    k_vT<<<dim3((SN + 31) / 32, DH / 32, BN * HN), 256, 0, stream>>>(
        bQKV + 2 * FD, bVt);
    k_fattn<<<dim3((SN + 63) / 64, HN, BN), 256, 0, stream>>>(
        bQKV, bQKV + FD, bVt, bO);
    k_mm<false, true><<<dim3(FD / 128, (MR + 127) / 128), 256, 0, stream>>>(
        bO, wOut + (size_t)l * FF, out_b + (size_t)l * FD, bOut, MR, FD, FD);
    k_add_ln<<<MR, 256, 0, stream>>>(src, srcb, bOut, ln1_g + (size_t)l * FD,
                                     ln1_b + (size_t)l * FD);
    k_mm<true, true><<<dim3(DF / 128, (MR + 127) / 128), 256, 0, stream>>>(
        srcb, wL1 + (size_t)l * DF * FD, l1_b + (size_t)l * DF, bFF, MR, DF,
        FD);
    k_mm<false, true><<<dim3(FD / 128, (MR + 127) / 128), 256, 0, stream>>>(
        bFF, wL2 + (size_t)l * FD * DF, l2_b + (size_t)l * FD, bOut, MR, FD,
        DF);
    k_add_ln<<<MR, 256, 0, stream>>>(src, srcb, bOut, ln2_g + (size_t)l * FD,
                                     ln2_b + (size_t)l * FD);
  }

  // ---- conv head ----
  k_convw<<<1024, 256, 0, stream>>>(emb_w, convW);
  k_pad<<<dim3(TN + 2, BN), 256, 0, stream>>>(srcb, srcPad);
  k_mmconv<<<dim3(FD / 128, (BN * TN) / 128), 256, 0, stream>>>(
      srcPad, convW, emb_b, (float*)d_out);
}